// Round 7
// baseline (1344.752 us; speedup 1.0000x reference)
//
#include <hip/hip_runtime.h>
#include <hip/hip_bf16.h>

#define NTOK 577
#define CH 768
#define NH 12
#define HD 64
#define M_ROWS 9232      // B * N
#define MPV 640          // m pitch of vT (5 * 128)

#define XHE 7090176      // M_ROWS * CH
#define WQH 1769472      // 3 * CH * CH
#define WPH 589824       // CH * CH

typedef _Float16 f16x8 __attribute__((ext_vector_type(8)));
typedef _Float16 f16x4 __attribute__((ext_vector_type(4)));
typedef _Float16 f16x2 __attribute__((ext_vector_type(2)));
typedef float f32x4 __attribute__((ext_vector_type(4)));

#define MFMA16(a, b, c) __builtin_amdgcn_mfma_f32_16x16x32_f16((a), (b), (c), 0, 0, 0)

// async global->LDS, 16 B per lane. LDS dest must be wave-linear (base+lane*16).
#define GLD16(gp, lp) __builtin_amdgcn_global_load_lds(               \
    (const __attribute__((address_space(1))) void*)(gp),              \
    (__attribute__((address_space(3))) void*)(lp), 16, 0, 0)

// XCD-chunked bijective swizzle (m204)
__device__ __forceinline__ int xcd_swz(int lin, int G) {
  int q = G >> 3, r = G & 7;
  int x = lin & 7, i = lin >> 3;
  return (x < r ? x * (q + 1) : r * (q + 1) + (x - r) * q) + i;
}

__device__ __forceinline__ float bf2f(unsigned int u16) {
  union { unsigned int i; float f; } x; x.i = u16 << 16; return x.f;
}

__device__ __forceinline__ float ldin(const void* p, size_t i, bool f32) {
  return f32 ? ((const float*)p)[i]
             : __bfloat162float(((const __hip_bfloat16*)p)[i]);
}

__device__ __forceinline__ f16x8 ld8_cvt(const void* p, size_t idx, bool f32) {
  f16x8 r;
  if (f32) {
    const float* f = (const float*)p + idx;
    const float4 u = *(const float4*)f;
    const float4 v = *(const float4*)(f + 4);
    r[0]=(_Float16)u.x; r[1]=(_Float16)u.y; r[2]=(_Float16)u.z; r[3]=(_Float16)u.w;
    r[4]=(_Float16)v.x; r[5]=(_Float16)v.y; r[6]=(_Float16)v.z; r[7]=(_Float16)v.w;
  } else {
    const unsigned short* s = (const unsigned short*)p + idx;
    uint4 u = *(const uint4*)s;
    unsigned int w0=u.x, w1=u.y, w2=u.z, w3=u.w;
    r[0]=(_Float16)bf2f(w0&0xffffu); r[1]=(_Float16)bf2f(w0>>16);
    r[2]=(_Float16)bf2f(w1&0xffffu); r[3]=(_Float16)bf2f(w1>>16);
    r[4]=(_Float16)bf2f(w2&0xffffu); r[5]=(_Float16)bf2f(w2>>16);
    r[6]=(_Float16)bf2f(w3&0xffffu); r[7]=(_Float16)bf2f(w3>>16);
  }
  return r;
}

// ---- Kernel 0: detect input dtype (fp32 vs bf16).
__global__ void detect_dtype(const unsigned short* __restrict__ xs,
                             int* __restrict__ flag) {
  __shared__ int cnt;
  if (threadIdx.x == 0) cnt = 0;
  __syncthreads();
  int local = 0;
  for (int i = threadIdx.x; i < 4096; i += 256) {
    unsigned int u = xs[2 * i];
    unsigned int e = (u >> 7) & 0xFFu;
    if (e >= 140u) local++;
  }
  atomicAdd(&cnt, local);
  __syncthreads();
  if (threadIdx.x == 0) *flag = (cnt > 100) ? 1 : 0;
}

// ---- Kernel 0b: convert x | Wqkv | Wproj into one contiguous f16 region.
__global__ __launch_bounds__(256) void cvt_all(
    const void* __restrict__ x, const void* __restrict__ wq,
    const void* __restrict__ wp, _Float16* __restrict__ dst,
    const int* __restrict__ flagp)
{
  const bool f32 = (*flagp != 0);
  size_t i = (size_t)(blockIdx.x * 256 + threadIdx.x) * 8;
  if (i >= (size_t)(XHE + WQH + WPH)) return;
  const void* src; size_t off;
  if (i < XHE)            { src = x;  off = i; }
  else if (i < XHE + WQH) { src = wq; off = i - XHE; }
  else                    { src = wp; off = i - XHE - WQH; }
  *(f16x8*)(dst + i) = ld8_cvt(src, off, f32);
}

// ---- Kernel 1: qkv = x @ Wqkv^T, m97 structure: global_load_lds width-16
// into linear [128][32] double-buffered LDS, source-side XOR swizzle.
__global__ __launch_bounds__(256) void gemm_qkv_mfma(
    const _Float16* __restrict__ X, const _Float16* __restrict__ W,
    _Float16* __restrict__ q, _Float16* __restrict__ k,
    _Float16* __restrict__ vT)
{
  __shared__ __align__(16) _Float16 As[2][128 * 32];
  __shared__ __align__(16) _Float16 Bs[2][128 * 32];
  const int swz = xcd_swz(blockIdx.x, 18 * 73);
  const int bx = swz % 18;                 // output-col tile (fast: shares X)
  const int m0 = (swz / 18) * 128;
  const int tid = threadIdx.x;
  const int lane = tid & 63, wave = tid >> 6;
  const int quad = lane >> 4, l16 = lane & 15;
  const int wm = wave & 1, wo = wave >> 1;
  const int t = bx / 6;                    // 0=q 1=k 2=v
  const int o0 = bx * 128;
  const int o0loc = o0 - t * CH;

  const int row0 = wave * 32 + (lane >> 2);
  const int ch8  = (((lane & 3) ^ ((lane >> 3) & 3)) << 3);  // swizzled src col
  const int ar0 = min(m0 + row0, M_ROWS - 1);
  const int ar1 = min(m0 + row0 + 16, M_ROWS - 1);
  const int br0 = o0 + row0;
  const int br1 = o0 + row0 + 16;
  const int dl0 = wave * 1024 + lane * 8;   // linear LDS dest (f16 idx)
  const int dl1 = dl0 + 512;

  GLD16(X + (size_t)ar0 * CH + ch8, &As[0][dl0]);
  GLD16(X + (size_t)ar1 * CH + ch8, &As[0][dl1]);
  GLD16(W + (size_t)br0 * CH + ch8, &Bs[0][dl0]);
  GLD16(W + (size_t)br1 * CH + ch8, &Bs[0][dl1]);

  const int rdc = ((quad ^ ((l16 >> 1) & 3)) << 3);      // swizzled read col
  const int rdA = (wm * 64 + l16) * 32 + rdc;
  const int rdB = (wo * 64 + l16) * 32 + rdc;

  f32x4 acc[4][4] = {};
  int cur = 0;
  for (int ks = 0; ks < CH / 32; ++ks) {
    __syncthreads();                       // drains vmcnt: tile ks ready
    if (ks + 1 < CH / 32) {
      const int kc = (ks + 1) * 32 + ch8;
      const int nb = cur ^ 1;
      GLD16(X + (size_t)ar0 * CH + kc, &As[nb][dl0]);
      GLD16(X + (size_t)ar1 * CH + kc, &As[nb][dl1]);
      GLD16(W + (size_t)br0 * CH + kc, &Bs[nb][dl0]);
      GLD16(W + (size_t)br1 * CH + kc, &Bs[nb][dl1]);
    }
    f16x8 af[4], bf_[4];
    #pragma unroll
    for (int i = 0; i < 4; ++i)
      af[i] = *(const f16x8*)&As[cur][rdA + i * 512];
    #pragma unroll
    for (int j = 0; j < 4; ++j)
      bf_[j] = *(const f16x8*)&Bs[cur][rdB + j * 512];
    #pragma unroll
    for (int i = 0; i < 4; ++i)
      #pragma unroll
      for (int j = 0; j < 4; ++j)
        acc[i][j] = MFMA16(af[i], bf_[j], acc[i][j]);
    cur ^= 1;
  }

  if (t < 2) {
    #pragma unroll
    for (int i = 0; i < 4; ++i) {
      #pragma unroll
      for (int rr = 0; rr < 4; ++rr) {
        int m = m0 + wm * 64 + i * 16 + quad * 4 + rr;
        if (m >= M_ROWS) continue;
        int b = m / NTOK, n = m - b * NTOK;
        #pragma unroll
        for (int j = 0; j < 4; ++j) {
          int o = o0loc + wo * 64 + j * 16 + l16;
          int h = o >> 6, dd = o & 63;
          _Float16 val = (_Float16)acc[i][j][rr];
          if (t == 0)
            q[((size_t)(b * NH + h) * NTOK + n) * HD + dd] = val;
          else
            k[((size_t)(b * NH + h) * NTOK + n) * HD + dd] = val;
        }
      }
    }
  } else {
    // vT epilogue: per-wave LDS micro-transpose of each 16x16 fragment.
    __syncthreads();                       // LDS reads of K-loop done
    _Float16* scrb = &As[0][0] + wave * 512;
    #pragma unroll
    for (int i = 0; i < 4; ++i) {
      #pragma unroll
      for (int j = 0; j < 4; ++j) {
        _Float16* scr = scrb + (j & 1) * 256;
        f16x4 wv;
        wv[0] = (_Float16)acc[i][j][0]; wv[1] = (_Float16)acc[i][j][1];
        wv[2] = (_Float16)acc[i][j][2]; wv[3] = (_Float16)acc[i][j][3];
        *(f16x4*)&scr[l16 * 16 + quad * 4] = wv;   // scr[dd][n_loc]
        asm volatile("s_waitcnt lgkmcnt(0)" ::: "memory");
        f16x4 rv = *(const f16x4*)&scr[(lane >> 2) * 16 + (lane & 3) * 4];
        int oc = o0loc + wo * 64 + j * 16 + (lane >> 2);
        int hh = oc >> 6, ddg = oc & 63;
        int mbase = m0 + wm * 64 + i * 16 + (lane & 3) * 4;
        int bb = mbase / NTOK, nn = mbase - bb * NTOK;
        _Float16* dst = &vT[((size_t)(bb * NH + hh) * HD + ddg) * MPV + nn];
        if (mbase + 3 < M_ROWS && nn + 3 < NTOK && !(nn & 1)) {
          f16x2 lo2, hi2;
          lo2[0] = rv[0]; lo2[1] = rv[1];
          hi2[0] = rv[2]; hi2[1] = rv[3];
          *(f16x2*)dst = lo2;
          *(f16x2*)(dst + 2) = hi2;
        } else {
          #pragma unroll
          for (int e = 0; e < 4; ++e) {
            int m = mbase + e;
            if (m < M_ROWS) {
              int b2 = m / NTOK, n2 = m - b2 * NTOK;
              vT[((size_t)(b2 * NH + hh) * HD + ddg) * MPV + n2] = rv[e];
            }
          }
        }
      }
    }
  }
}

// ---- zero the m-pad of vT (m in [577,640)).
__global__ void zerofill_vt(_Float16* __restrict__ vT) {
  int idx = blockIdx.x * 256 + threadIdx.x;
  int r = idx >> 6, c = idx & 63;
  if (r < 16 * NH * HD && c < MPV - NTOK)
    vT[(size_t)r * MPV + NTOK + c] = (_Float16)0.f;
}

// ---- Kernel 2 (fused attention): per (batch, 8-row n-tile) block.
// Identical math to the round-5 kernel (correctness-verified); two changes:
//   (a) batch->XCD affinity: block lin -> XCD lin%8 (hardware round-robin),
//       b = (lin>>3)/73*8 + (lin&7). All 73 blocks of a batch run on one
//       XCD, so its K+vT (1.87 MB) stays L2-resident: fixes round-5's
//       1.78 GB L2-miss FETCH (each block re-streamed the whole batch).
//   (b) __launch_bounds__(512, 2): true occupancy is 1 block/CU (142 KB
//       LDS) = 2 waves/SIMD -> 256-VGPR budget for the allocator.
__global__ __launch_bounds__(512, 2) void attn_fused(
    const _Float16* __restrict__ q, const _Float16* __restrict__ k,
    const _Float16* __restrict__ vT, const void* __restrict__ Wpre,
    const void* __restrict__ Wpost, const int* __restrict__ flagp,
    _Float16* __restrict__ o1)
{
  extern __shared__ __align__(16) char smem[];
  _Float16* Eg   = (_Float16*)smem;                     // [12][8][648]
  _Float16* qs   = Eg + 12 * 8 * 648;                   // [12][8][72]
  float*    wsum = (float*)(qs + 12 * 8 * 72);          // [8][12][8]
  float*    wp   = wsum + 8 * 12 * 8;                   // [144]
  _Float16* w2h  = (_Float16*)(wp + 144);               // [144]
  float*    rinv = (float*)(w2h + 144);                 // [12][8]

  const bool f32 = (*flagp != 0);
  const int tid = threadIdx.x;
  const int xcd = blockIdx.x & 7;
  const int tt  = blockIdx.x >> 3;         // 0..145
  const int b   = (tt / 73) * 8 + xcd;     // batch pinned to XCD
  const int n0  = (tt % 73) * 8;
  const int lane = tid & 63, w = tid >> 6;
  const int quad = lane >> 4, l16 = lane & 15;
  const int nloc = l16 & 7;

  if (tid < 144) {
    wp[tid]  = ldin(Wpre, tid, f32) * 0.125f;           // fold d^-0.5
    w2h[tid] = (_Float16)ldin(Wpost, tid, f32);
  }
  // stage q tile: 12h x 8n x 64d (rows >= NTOK clamped; outputs masked later)
  for (int t = tid; t < 768; t += 512) {
    int h = t >> 6, n = (t >> 3) & 7, c = t & 7;
    int gn = min(n0 + n, NTOK - 1);
    *(f16x8*)&qs[h * 576 + n * 72 + c * 8] =
        *(const f16x8*)(q + ((size_t)(b * NH + h) * NTOK + gn) * HD + c * 8);
  }
  __syncthreads();

  // ---- pass 1: wave w owns m in [w*80, w*80+80)
  float rs[NH][4];
  #pragma unroll
  for (int g = 0; g < NH; ++g)
    #pragma unroll
    for (int r = 0; r < 4; ++r) rs[g][r] = 0.f;

  const int mw0 = w * 80;
  for (int mt = 0; mt < 5; ++mt) {
    const int m = mw0 + mt * 16 + l16;
    const int mk = min(m, NTOK - 1);
    f32x4 acc[NH];
    #pragma unroll
    for (int h = 0; h < NH; ++h) {
      f16x8 q0 = *(const f16x8*)&qs[h * 576 + nloc * 72 + quad * 8];
      f16x8 q1 = *(const f16x8*)&qs[h * 576 + nloc * 72 + quad * 8 + 32];
      const _Float16* kp = k + ((size_t)(b * NH + h) * NTOK + mk) * HD + quad * 8;
      f16x8 k0 = *(const f16x8*)kp;
      f16x8 k1 = *(const f16x8*)(kp + 32);
      f32x4 z = {0.f, 0.f, 0.f, 0.f};
      z = MFMA16(q0, k0, z);
      acc[h] = MFMA16(q1, k1, z);      // C[n=quad*4+r][m=l16]; rows 8..15 dup
    }
    const bool vm = (m < NTOK);
    #pragma unroll
    for (int g = 0; g < NH; ++g) {
      float s0 = 0.f, s1 = 0.f, s2 = 0.f, s3 = 0.f;
      #pragma unroll
      for (int h = 0; h < NH; ++h) {
        const float ww = wp[g * NH + h];
        s0 += ww * acc[h][0]; s1 += ww * acc[h][1];
        s2 += ww * acc[h][2]; s3 += ww * acc[h][3];
      }
      float e0 = vm ? __expf(s0) : 0.f;
      float e1 = vm ? __expf(s1) : 0.f;
      float e2 = vm ? __expf(s2) : 0.f;
      float e3 = vm ? __expf(s3) : 0.f;
      if (quad < 2) {                      // rows n = quad*4 .. +3 (valid < 8)
        _Float16* er = &Eg[g * 5184 + (quad * 4) * 648 + m];
        er[0]    = (_Float16)e0;
        er[648]  = (_Float16)e1;
        er[1296] = (_Float16)e2;
        er[1944] = (_Float16)e3;
      }
      rs[g][0] += e0; rs[g][1] += e1; rs[g][2] += e2; rs[g][3] += e3;
    }
  }
  #pragma unroll
  for (int g = 0; g < NH; ++g)
    #pragma unroll
    for (int r = 0; r < 4; ++r) {
      float t = rs[g][r];
      t += __shfl_xor(t, 1); t += __shfl_xor(t, 2);
      t += __shfl_xor(t, 4); t += __shfl_xor(t, 8);
      rs[g][r] = t;
    }
  if (l16 == 0 && quad < 2) {
    #pragma unroll
    for (int g = 0; g < NH; ++g)
      #pragma unroll
      for (int r = 0; r < 4; ++r)
        wsum[(w * NH + g) * 8 + quad * 4 + r] = rs[g][r];
  }
  __syncthreads();
  if (tid < 96) {
    int g = tid >> 3, n = tid & 7;
    float S = 0.f;
    #pragma unroll
    for (int ww = 0; ww < 8; ++ww) S += wsum[(ww * NH + g) * 8 + n];
    rinv[g * 8 + n] = (S > 0.f) ? 1.f / S : 0.f;
  }
  __syncthreads();

  // ---- pass 2: wave w -> g in [gB, gB+3), d-half dh
  const int gB = (w >> 1) * 3, dh = w & 1;
  _Float16 rl[NH];
  #pragma unroll
  for (int h = 0; h < NH; ++h) rl[h] = (_Float16)rinv[h * 8 + nloc];
  f32x4 O[3][2];
  #pragma unroll
  for (int j = 0; j < 3; ++j) {
    O[j][0] = (f32x4){0.f, 0.f, 0.f, 0.f};
    O[j][1] = (f32x4){0.f, 0.f, 0.f, 0.f};
  }
  for (int kc = 0; kc < 20; ++kc) {
    const int mo = kc * 32 + quad * 8;
    f16x8 evn[NH];
    #pragma unroll
    for (int h = 0; h < NH; ++h)
      evn[h] = (*(const f16x8*)&Eg[h * 5184 + nloc * 648 + mo]) * rl[h];
    #pragma unroll
    for (int j = 0; j < 3; ++j) {
      const int g = gB + j;
      f16x8 p = evn[0] * w2h[g * NH + 0];
      #pragma unroll
      for (int h = 1; h < NH; ++h) p += evn[h] * w2h[g * NH + h];
      #pragma unroll
      for (int dtl = 0; dtl < 2; ++dtl) {
        const int dt = dh * 2 + dtl;
        f16x8 bv = *(const f16x8*)(
            vT + ((size_t)(b * NH + g) * HD + dt * 16 + l16) * MPV + mo);
        O[j][dtl] = MFMA16(p, bv, O[j][dtl]);   // C[n=quad*4+r][d=l16]
      }
    }
  }
  #pragma unroll
  for (int j = 0; j < 3; ++j)
    #pragma unroll
    for (int dtl = 0; dtl < 2; ++dtl)
      #pragma unroll
      for (int r = 0; r < 4; ++r) {
        int n = quad * 4 + r;
        if (n < 8 && n0 + n < NTOK)
          o1[((size_t)b * NTOK + n0 + n) * CH + (gB + j) * HD
             + (dh * 2 + dtl) * 16 + l16] = (_Float16)O[j][dtl][r];
      }
}

// ---- Kernel 4: out = o1 @ Wproj^T + bproj, m97-style staging.
__global__ __launch_bounds__(256) void gemm_proj_mfma(
    const _Float16* __restrict__ A, const _Float16* __restrict__ W,
    const void* __restrict__ bias, const int* __restrict__ flagp,
    void* __restrict__ out)
{
  const bool f32 = (*flagp != 0);
  __shared__ __align__(16) _Float16 As[2][128 * 32];
  __shared__ __align__(16) _Float16 Bs[2][128 * 32];
  const int swz = xcd_swz(blockIdx.x, 6 * 73);
  const int o0 = (swz % 6) * 128;
  const int m0 = (swz / 6) * 128;
  const int tid = threadIdx.x;
  const int lane = tid & 63, wave = tid >> 6;
  const int quad = lane >> 4, l16 = lane & 15;
  const int wm = wave & 1, wo = wave >> 1;

  const int row0 = wave * 32 + (lane >> 2);
  const int ch8  = (((lane & 3) ^ ((lane >> 3) & 3)) << 3);
  const int ar0 = min(m0 + row0, M_ROWS - 1);
  const int ar1 = min(m0 + row0 + 16, M_ROWS - 1);
  const int br0 = o0 + row0;
  const int br1 = o0 + row0 + 16;
  const int dl0 = wave * 1024 + lane * 8;
  const int dl1 = dl0 + 512;

  GLD16(A + (size_t)ar0 * CH + ch8, &As[0][dl0]);
  GLD16(A + (size_t)ar1 * CH + ch8, &As[0][dl1]);
  GLD16(W + (size_t)br0 * CH + ch8, &Bs[0][dl0]);
  GLD16(W + (size_t)br1 * CH + ch8, &Bs[0][dl1]);

  const int rdc = ((quad ^ ((l16 >> 1) & 3)) << 3);
  const int rdA = (wm * 64 + l16) * 32 + rdc;
  const int rdB = (wo * 64 + l16) * 32 + rdc;

  f32x4 acc[4][4] = {};
  int cur = 0;
  for (int ks = 0; ks < CH / 32; ++ks) {
    __syncthreads();
    if (ks + 1 < CH / 32) {
      const int kc = (ks + 1) * 32 + ch8;
      const int nb = cur ^ 1;
      GLD16(A + (size_t)ar0 * CH + kc, &As[nb][dl0]);
      GLD16(A + (size_t)ar1 * CH + kc, &As[nb][dl1]);
      GLD16(W + (size_t)br0 * CH + kc, &Bs[nb][dl0]);
      GLD16(W + (size_t)br1 * CH + kc, &Bs[nb][dl1]);
    }
    f16x8 af[4], bf_[4];
    #pragma unroll
    for (int i = 0; i < 4; ++i)
      af[i] = *(const f16x8*)&As[cur][rdA + i * 512];
    #pragma unroll
    for (int j = 0; j < 4; ++j)
      bf_[j] = *(const f16x8*)&Bs[cur][rdB + j * 512];
    #pragma unroll
    for (int i = 0; i < 4; ++i)
      #pragma unroll
      for (int j = 0; j < 4; ++j)
        acc[i][j] = MFMA16(af[i], bf_[j], acc[i][j]);
    cur ^= 1;
  }

  #pragma unroll
  for (int i = 0; i < 4; ++i) {
    #pragma unroll
    for (int rr = 0; rr < 4; ++rr) {
      int m = m0 + wm * 64 + i * 16 + quad * 4 + rr;
      if (m >= M_ROWS) continue;
      #pragma unroll
      for (int j = 0; j < 4; ++j) {
        int o = o0 + wo * 64 + j * 16 + l16;
        float val = acc[i][j][rr] + ldin(bias, o, f32);
        if (f32) ((float*)out)[(size_t)m * CH + o] = val;
        else ((__hip_bfloat16*)out)[(size_t)m * CH + o] = __float2bfloat16(val);
      }
    }
  }
}

extern "C" void kernel_launch(void* const* d_in, const int* in_sizes, int n_in,
                              void* d_out, int out_size, void* d_ws, size_t ws_size,
                              hipStream_t stream) {
  const void* x     = d_in[0];
  const void* Wqkv  = d_in[1];
  const void* Wproj = d_in[2];
  const void* bproj = d_in[3];
  const void* Wpre  = d_in[4];
  const void* Wpost = d_in[5];

  int* flag = (int*)d_ws;
  _Float16* ws = (_Float16*)((char*)d_ws + 16);
  const size_t QE  = (size_t)16 * NH * NTOK * HD;   // 7,090,176
  const size_t VTE = (size_t)16 * NH * HD * MPV;    // 7,864,320

  _Float16* Xh  = ws;
  _Float16* Wqh = Xh + XHE;
  _Float16* Wph = Wqh + WQH;
  _Float16* q   = Wph + WPH;
  _Float16* k   = q + QE;
  _Float16* vT  = k + QE;
  _Float16* o1  = vT + VTE;

  // attn_fused LDS: Eg 124416 + qs 13824 + wsum 3072 + wp 576 + w2h 288
  //               + rinv 384 = 142,560 B  (> 64 KB static limit -> dynamic)
  const size_t SMEM = 142560;
  hipFuncSetAttribute((const void*)attn_fused,
                      hipFuncAttributeMaxDynamicSharedMemorySize, (int)SMEM);

  dim3 blk(256);
  hipLaunchKernelGGL(detect_dtype, dim3(1), blk, 0, stream,
                     (const unsigned short*)x, flag);
  hipLaunchKernelGGL(cvt_all, dim3((XHE + WQH + WPH) / 8 / 256 + 1), blk, 0,
                     stream, x, Wqkv, Wproj, Xh, flag);
  hipLaunchKernelGGL(gemm_qkv_mfma, dim3(18 * 73), blk, 0, stream,
                     Xh, Wqh, q, k, vT);
  hipLaunchKernelGGL(zerofill_vt, dim3(16 * NH * HD * 64 / 256), blk, 0, stream, vT);
  hipLaunchKernelGGL(attn_fused, dim3(16 * 73), dim3(512), SMEM, stream,
                     q, k, vT, Wpre, Wpost, flag, o1);
  hipLaunchKernelGGL(gemm_proj_mfma, dim3(6 * 73), blk, 0, stream,
                     o1, Wph, bproj, flag, d_out);
}

// Round 8
// 537.287 us; speedup vs baseline: 2.5029x; 2.5029x over previous
//
#include <hip/hip_runtime.h>
#include <hip/hip_bf16.h>

#define NTOK 577
#define CH 768
#define NH 12
#define HD 64
#define M_ROWS 9232      // B * N
#define NPAD 592         // n pitch of E
#define MPV 640          // m pitch of vT and E (5 * 128)
#define ESP 72           // qk_exp LDS E-tile pitch (f16): 144 B = 9*16 aligned

#define XHE 7090176      // M_ROWS * CH
#define WQH 1769472      // 3 * CH * CH
#define WPH 589824       // CH * CH

typedef _Float16 f16x8 __attribute__((ext_vector_type(8)));
typedef _Float16 f16x4 __attribute__((ext_vector_type(4)));
typedef _Float16 f16x2 __attribute__((ext_vector_type(2)));
typedef float f32x4 __attribute__((ext_vector_type(4)));

#define MFMA16(a, b, c) __builtin_amdgcn_mfma_f32_16x16x32_f16((a), (b), (c), 0, 0, 0)

// barrier that does NOT drain vmcnt (LDS deps need lgkmcnt only)
#define BAR() asm volatile("s_waitcnt lgkmcnt(0)\n\ts_barrier" ::: "memory")

// async global->LDS, 16 B per lane. LDS dest must be wave-linear (base+lane*16).
#define GLD16(gp, lp) __builtin_amdgcn_global_load_lds(               \
    (const __attribute__((address_space(1))) void*)(gp),              \
    (__attribute__((address_space(3))) void*)(lp), 16, 0, 0)

// XCD-chunked bijective swizzle (m204)
__device__ __forceinline__ int xcd_swz(int lin, int G) {
  int q = G >> 3, r = G & 7;
  int x = lin & 7, i = lin >> 3;
  return (x < r ? x * (q + 1) : r * (q + 1) + (x - r) * q) + i;
}

__device__ __forceinline__ float bf2f(unsigned int u16) {
  union { unsigned int i; float f; } x; x.i = u16 << 16; return x.f;
}

__device__ __forceinline__ float ldin(const void* p, size_t i, bool f32) {
  return f32 ? ((const float*)p)[i]
             : __bfloat162float(((const __hip_bfloat16*)p)[i]);
}

__device__ __forceinline__ f16x8 ld8_cvt(const void* p, size_t idx, bool f32) {
  f16x8 r;
  if (f32) {
    const float* f = (const float*)p + idx;
    const float4 u = *(const float4*)f;
    const float4 v = *(const float4*)(f + 4);
    r[0]=(_Float16)u.x; r[1]=(_Float16)u.y; r[2]=(_Float16)u.z; r[3]=(_Float16)u.w;
    r[4]=(_Float16)v.x; r[5]=(_Float16)v.y; r[6]=(_Float16)v.z; r[7]=(_Float16)v.w;
  } else {
    const unsigned short* s = (const unsigned short*)p + idx;
    uint4 u = *(const uint4*)s;
    unsigned int w0=u.x, w1=u.y, w2=u.z, w3=u.w;
    r[0]=(_Float16)bf2f(w0&0xffffu); r[1]=(_Float16)bf2f(w0>>16);
    r[2]=(_Float16)bf2f(w1&0xffffu); r[3]=(_Float16)bf2f(w1>>16);
    r[4]=(_Float16)bf2f(w2&0xffffu); r[5]=(_Float16)bf2f(w2>>16);
    r[6]=(_Float16)bf2f(w3&0xffffu); r[7]=(_Float16)bf2f(w3>>16);
  }
  return r;
}

// ---- Kernel 0: detect input dtype (fp32 vs bf16).
__global__ void detect_dtype(const unsigned short* __restrict__ xs,
                             int* __restrict__ flag) {
  __shared__ int cnt;
  if (threadIdx.x == 0) cnt = 0;
  __syncthreads();
  int local = 0;
  for (int i = threadIdx.x; i < 4096; i += 256) {
    unsigned int u = xs[2 * i];
    unsigned int e = (u >> 7) & 0xFFu;
    if (e >= 140u) local++;
  }
  atomicAdd(&cnt, local);
  __syncthreads();
  if (threadIdx.x == 0) *flag = (cnt > 100) ? 1 : 0;
}

// ---- Kernel 0b: convert x | Wqkv | Wproj into one contiguous f16 region.
__global__ __launch_bounds__(256) void cvt_all(
    const void* __restrict__ x, const void* __restrict__ wq,
    const void* __restrict__ wp, _Float16* __restrict__ dst,
    const int* __restrict__ flagp)
{
  const bool f32 = (*flagp != 0);
  size_t i = (size_t)(blockIdx.x * 256 + threadIdx.x) * 8;
  if (i >= (size_t)(XHE + WQH + WPH)) return;
  const void* src; size_t off;
  if (i < XHE)            { src = x;  off = i; }
  else if (i < XHE + WQH) { src = wq; off = i - XHE; }
  else                    { src = wp; off = i - XHE - WQH; }
  *(f16x8*)(dst + i) = ld8_cvt(src, off, f32);
}

// ---- Kernel 1: qkv = x @ Wqkv^T, m97 structure: global_load_lds width-16
// into linear [128][32] double-buffered LDS, source-side XOR swizzle.
__global__ __launch_bounds__(256) void gemm_qkv_mfma(
    const _Float16* __restrict__ X, const _Float16* __restrict__ W,
    _Float16* __restrict__ q, _Float16* __restrict__ k,
    _Float16* __restrict__ vT)
{
  __shared__ __align__(16) _Float16 As[2][128 * 32];
  __shared__ __align__(16) _Float16 Bs[2][128 * 32];
  const int swz = xcd_swz(blockIdx.x, 18 * 73);
  const int bx = swz % 18;                 // output-col tile (fast: shares X)
  const int m0 = (swz / 18) * 128;
  const int tid = threadIdx.x;
  const int lane = tid & 63, wave = tid >> 6;
  const int quad = lane >> 4, l16 = lane & 15;
  const int wm = wave & 1, wo = wave >> 1;
  const int t = bx / 6;                    // 0=q 1=k 2=v
  const int o0 = bx * 128;
  const int o0loc = o0 - t * CH;

  const int row0 = wave * 32 + (lane >> 2);
  const int ch8  = (((lane & 3) ^ ((lane >> 3) & 3)) << 3);  // swizzled src col
  const int ar0 = min(m0 + row0, M_ROWS - 1);
  const int ar1 = min(m0 + row0 + 16, M_ROWS - 1);
  const int br0 = o0 + row0;
  const int br1 = o0 + row0 + 16;
  const int dl0 = wave * 1024 + lane * 8;   // linear LDS dest (f16 idx)
  const int dl1 = dl0 + 512;

  GLD16(X + (size_t)ar0 * CH + ch8, &As[0][dl0]);
  GLD16(X + (size_t)ar1 * CH + ch8, &As[0][dl1]);
  GLD16(W + (size_t)br0 * CH + ch8, &Bs[0][dl0]);
  GLD16(W + (size_t)br1 * CH + ch8, &Bs[0][dl1]);

  const int rdc = ((quad ^ ((l16 >> 1) & 3)) << 3);      // swizzled read col
  const int rdA = (wm * 64 + l16) * 32 + rdc;
  const int rdB = (wo * 64 + l16) * 32 + rdc;

  f32x4 acc[4][4] = {};
  int cur = 0;
  for (int ks = 0; ks < CH / 32; ++ks) {
    __syncthreads();                       // drains vmcnt: tile ks ready
    if (ks + 1 < CH / 32) {
      const int kc = (ks + 1) * 32 + ch8;
      const int nb = cur ^ 1;
      GLD16(X + (size_t)ar0 * CH + kc, &As[nb][dl0]);
      GLD16(X + (size_t)ar1 * CH + kc, &As[nb][dl1]);
      GLD16(W + (size_t)br0 * CH + kc, &Bs[nb][dl0]);
      GLD16(W + (size_t)br1 * CH + kc, &Bs[nb][dl1]);
    }
    f16x8 af[4], bf_[4];
    #pragma unroll
    for (int i = 0; i < 4; ++i)
      af[i] = *(const f16x8*)&As[cur][rdA + i * 512];
    #pragma unroll
    for (int j = 0; j < 4; ++j)
      bf_[j] = *(const f16x8*)&Bs[cur][rdB + j * 512];
    #pragma unroll
    for (int i = 0; i < 4; ++i)
      #pragma unroll
      for (int j = 0; j < 4; ++j)
        acc[i][j] = MFMA16(af[i], bf_[j], acc[i][j]);
    cur ^= 1;
  }

  if (t < 2) {
    #pragma unroll
    for (int i = 0; i < 4; ++i) {
      #pragma unroll
      for (int rr = 0; rr < 4; ++rr) {
        int m = m0 + wm * 64 + i * 16 + quad * 4 + rr;
        if (m >= M_ROWS) continue;
        int b = m / NTOK, n = m - b * NTOK;
        #pragma unroll
        for (int j = 0; j < 4; ++j) {
          int o = o0loc + wo * 64 + j * 16 + l16;
          int h = o >> 6, dd = o & 63;
          _Float16 val = (_Float16)acc[i][j][rr];
          if (t == 0)
            q[((size_t)(b * NH + h) * NTOK + n) * HD + dd] = val;
          else
            k[((size_t)(b * NH + h) * NTOK + n) * HD + dd] = val;
        }
      }
    }
  } else {
    // vT epilogue: per-wave LDS micro-transpose of each 16x16 fragment.
    __syncthreads();                       // LDS reads of K-loop done
    _Float16* scrb = &As[0][0] + wave * 512;
    #pragma unroll
    for (int i = 0; i < 4; ++i) {
      #pragma unroll
      for (int j = 0; j < 4; ++j) {
        _Float16* scr = scrb + (j & 1) * 256;
        f16x4 wv;
        wv[0] = (_Float16)acc[i][j][0]; wv[1] = (_Float16)acc[i][j][1];
        wv[2] = (_Float16)acc[i][j][2]; wv[3] = (_Float16)acc[i][j][3];
        *(f16x4*)&scr[l16 * 16 + quad * 4] = wv;   // scr[dd][n_loc]
        asm volatile("s_waitcnt lgkmcnt(0)" ::: "memory");
        f16x4 rv = *(const f16x4*)&scr[(lane >> 2) * 16 + (lane & 3) * 4];
        int oc = o0loc + wo * 64 + j * 16 + (lane >> 2);
        int hh = oc >> 6, ddg = oc & 63;
        int mbase = m0 + wm * 64 + i * 16 + (lane & 3) * 4;
        int bb = mbase / NTOK, nn = mbase - bb * NTOK;
        _Float16* dst = &vT[((size_t)(bb * NH + hh) * HD + ddg) * MPV + nn];
        if (mbase + 3 < M_ROWS && nn + 3 < NTOK && !(nn & 1)) {
          f16x2 lo2, hi2;
          lo2[0] = rv[0]; lo2[1] = rv[1];
          hi2[0] = rv[2]; hi2[1] = rv[3];
          *(f16x2*)dst = lo2;
          *(f16x2*)(dst + 2) = hi2;
        } else {
          #pragma unroll
          for (int e = 0; e < 4; ++e) {
            int m = mbase + e;
            if (m < M_ROWS) {
              int b2 = m / NTOK, n2 = m - b2 * NTOK;
              vT[((size_t)(b2 * NH + hh) * HD + ddg) * MPV + n2] = rv[e];
            }
          }
        }
      }
    }
  }
}

// ---- zero the m-pad of vT (m in [577,640)).
__global__ void zerofill_vt(_Float16* __restrict__ vT) {
  int idx = blockIdx.x * 256 + threadIdx.x;
  int r = idx >> 6, c = idx & 63;
  if (r < 16 * NH * HD && c < MPV - NTOK)
    vT[(size_t)r * MPV + NTOK + c] = (_Float16)0.f;
}

// ---- Kernel 2: QK^T + Wpre mix + exp -> E (unnormalized) + partial rowsums.
__global__ __launch_bounds__(256) void qk_exp(
    const _Float16* __restrict__ q, const _Float16* __restrict__ k,
    const void* __restrict__ Wpre, const int* __restrict__ flagp,
    _Float16* __restrict__ E, float* __restrict__ Rp, int b0, int cb)
{
  const bool f32 = (*flagp != 0);
  __shared__ float wp[NH * NH];
  __shared__ _Float16 Es[NH * 16 * ESP];   // [g][n(16)][m(64)], pitch 72
  const int tid = threadIdx.x;
  if (tid < NH * NH) wp[tid] = ldin(Wpre, tid, f32) * 0.125f;  // fold scale
  __syncthreads();
  const int swz = xcd_swz(blockIdx.x, 370 * cb);
  const int bl = swz / 370;
  const int ny = (swz % 370) / 10;
  const int bx = swz % 10;
  const int lane = tid & 63, wave = tid >> 6;
  const int quad = lane >> 4, l16 = lane & 15;
  const int b = b0 + bl;
  const int n0 = ny * 16;
  const int m0 = bx * 64 + wave * 16;
  const int nq = min(n0 + l16, NTOK - 1);
  const int mk = min(m0 + l16, NTOK - 1);
  const size_t qbase = ((size_t)b * NH * NTOK + nq) * HD + quad * 8;
  const size_t kbase = ((size_t)b * NH * NTOK + mk) * HD + quad * 8;
  f32x4 acc[NH];
  #pragma unroll
  for (int h = 0; h < NH; ++h) {
    const size_t ho = (size_t)h * NTOK * HD;
    f16x8 a0 = *(const f16x8*)(q + qbase + ho);
    f16x8 bb0 = *(const f16x8*)(k + kbase + ho);
    f16x8 a1 = *(const f16x8*)(q + qbase + ho + 32);
    f16x8 bb1 = *(const f16x8*)(k + kbase + ho + 32);
    f32x4 z = {0.f, 0.f, 0.f, 0.f};
    z = MFMA16(a0, bb0, z);
    acc[h] = MFMA16(a1, bb1, z);
  }
  const int mloc = wave * 16 + l16;          // col within 64-wide tile
  const bool valid = (m0 + l16 < NTOK);
  #pragma unroll
  for (int g = 0; g < NH; ++g) {
    float s0 = 0.f, s1 = 0.f, s2 = 0.f, s3 = 0.f;
    #pragma unroll
    for (int h = 0; h < NH; ++h) {
      float w = wp[g * NH + h];
      s0 += w * acc[h][0]; s1 += w * acc[h][1];
      s2 += w * acc[h][2]; s3 += w * acc[h][3];
    }
    Es[(g * 16 + quad * 4 + 0) * ESP + mloc] = (_Float16)(valid ? __expf(s0) : 0.f);
    Es[(g * 16 + quad * 4 + 1) * ESP + mloc] = (_Float16)(valid ? __expf(s1) : 0.f);
    Es[(g * 16 + quad * 4 + 2) * ESP + mloc] = (_Float16)(valid ? __expf(s2) : 0.f);
    Es[(g * 16 + quad * 4 + 3) * ESP + mloc] = (_Float16)(valid ? __expf(s3) : 0.f);
  }
  __syncthreads();
  // cooperative full-line store: 8 lanes x 16 B = 128 B contiguous per row
  const int sub = tid & 7;
  const int rbk = tid >> 3;                  // 32 rows per pass
  #pragma unroll
  for (int it = 0; it < 6; ++it) {
    int idx = it * 32 + rbk;                 // 0..191
    int g = idx >> 4, n = idx & 15;
    f16x8 vv = *(const f16x8*)&Es[(g * 16 + n) * ESP + sub * 8];
    *(f16x8*)&E[((size_t)(bl * NH + g) * NPAD + n0 + n) * MPV + bx * 64 + sub * 8] = vv;
  }
  // partial rowsum of this block's 64 m-cols, per (g, n): Rp[b][g][bx][n]
  if (tid < NH * 16) {
    const _Float16* row = &Es[tid * ESP];
    float tot = 0.f;
    #pragma unroll
    for (int c = 0; c < 8; ++c) {
      f16x8 t = *(const f16x8*)&row[c * 8];
      #pragma unroll
      for (int j = 0; j < 8; ++j) tot += (float)t[j];
    }
    Rp[(((size_t)b * NH + (tid >> 4)) * 10 + bx) * NPAD + n0 + (tid & 15)] = tot;
  }
}

// ---- Kernel 3: pv_mix3 — 8-row n-tiles, NO m-split, NO f32 partials.
// Grid 73*cb blocks (same parallelism as the old z-split without the
// 171 MB Op round-trip + reduce kernel). Every E element still read once.
// MFMA A-rows duplicated (n = l16&7); only C rows n<8 stored (round-5
// verified pattern). P2s 24.6 KB (round-4's XOR swizzle, pitch 128).
__global__ __launch_bounds__(256) void pv_mix3(
    const _Float16* __restrict__ E, const _Float16* __restrict__ vT,
    const float* __restrict__ Rp, const void* __restrict__ Wpost,
    const int* __restrict__ flagp, _Float16* __restrict__ o1, int b0, int cb)
{
  const bool f32 = (*flagp != 0);
  __shared__ _Float16 P2s[NH * 8 * 128];    // [g][n8][m128], col ^ (n*8)
  __shared__ _Float16 w2s[NH * NH];
  __shared__ _Float16 rinvs[NH * 8];
  const int swz = xcd_swz(blockIdx.x, 73 * cb);
  const int bl = swz / 73;
  const int nx = swz % 73;
  const int tid = threadIdx.x;
  const int lane = tid & 63, w = tid >> 6;
  const int quad = lane >> 4, l16 = lane & 15;
  const int nn = l16 & 7;
  const int n0 = nx * 8;
  const int b = b0 + bl;
  if (tid < NH * NH) w2s[tid] = (_Float16)ldin(Wpost, tid, f32);
  if (tid < NH * 8) {
    float tot = 0.f;
    #pragma unroll
    for (int mb = 0; mb < 10; ++mb)
      tot += Rp[(((size_t)b * NH + (tid >> 3)) * 10 + mb) * NPAD + n0 + (tid & 7)];
    rinvs[tid] = (_Float16)(tot > 0.f ? 1.f / tot : 0.f);
  }
  __syncthreads();
  _Float16 rloc[NH];
  #pragma unroll
  for (int h = 0; h < NH; ++h) rloc[h] = rinvs[h * 8 + nn];

  f32x4 O[3][4];
  #pragma unroll
  for (int j = 0; j < 3; ++j)
    #pragma unroll
    for (int dt = 0; dt < 4; ++dt) O[j][dt] = (f32x4){0.f, 0.f, 0.f, 0.f};
  const int gg0 = w * 3;
  const int swzc = nn << 3;                 // column XOR for row nn

  const size_t ebase = ((size_t)(bl * NH) * NPAD + n0 + nn) * MPV
                     + w * 32 + quad * 8;
  const size_t estep = (size_t)NPAD * MPV;  // per-head stride
  f16x8 ev0[NH], ev1[NH];
  #pragma unroll
  for (int h = 0; h < NH; ++h)
    ev0[h] = *(const f16x8*)&E[ebase + h * estep];
  #pragma unroll
  for (int i = 0; i < 5; ++i) {
    f16x8* curp = (i & 1) ? ev1 : ev0;
    f16x8* nxtp = (i & 1) ? ev0 : ev1;
    BAR();                                  // previous P2s readers done
    if (i + 1 < 5) {                        // prefetch next m-chunk; stays
      #pragma unroll                        // in flight across both BARs
      for (int h = 0; h < NH; ++h)
        nxtp[h] = *(const f16x8*)&E[ebase + h * estep + (i + 1) * 128];
    }
    #pragma unroll
    for (int h = 0; h < NH; ++h) curp[h] *= rloc[h];
    #pragma unroll
    for (int gp = 0; gp < NH; ++gp) {
      f16x8 p = curp[0] * w2s[gp * NH + 0];
      #pragma unroll
      for (int h = 1; h < NH; ++h) p += curp[h] * w2s[gp * NH + h];
      if (l16 < 8)                          // lanes 8-15 hold duplicate data
        *(f16x8*)&P2s[gp * 1024 + nn * 128 + ((w * 32 + quad * 8) ^ swzc)] = p;
    }
    BAR();
    #pragma unroll
    for (int kc = 0; kc < 4; ++kc) {
      #pragma unroll
      for (int j = 0; j < 3; ++j) {
        const int g = gg0 + j;
        f16x8 a = *(const f16x8*)&P2s[g * 1024 + nn * 128
                                      + ((kc * 32 + quad * 8) ^ swzc)];
        #pragma unroll
        for (int dt = 0; dt < 4; ++dt) {
          f16x8 bv = *(const f16x8*)(
              vT + ((size_t)(b * NH + g) * HD + dt * 16 + l16) * MPV
                 + i * 128 + kc * 32 + quad * 8);
          O[j][dt] = MFMA16(a, bv, O[j][dt]);   // C rows 8-15 = dup of 0-7
        }
      }
    }
  }
  #pragma unroll
  for (int j = 0; j < 3; ++j)
    #pragma unroll
    for (int dt = 0; dt < 4; ++dt)
      #pragma unroll
      for (int r = 0; r < 4; ++r) {
        int n = quad * 4 + r;               // only quad<2 rows are real
        if (n < 8 && n0 + n < NTOK)
          o1[((size_t)b * NTOK + n0 + n) * CH + (gg0 + j) * HD + dt * 16 + l16] =
              (_Float16)O[j][dt][r];
      }
}

// ---- Kernel 4: out = o1 @ Wproj^T + bproj, m97-style staging.
__global__ __launch_bounds__(256) void gemm_proj_mfma(
    const _Float16* __restrict__ A, const _Float16* __restrict__ W,
    const void* __restrict__ bias, const int* __restrict__ flagp,
    void* __restrict__ out)
{
  const bool f32 = (*flagp != 0);
  __shared__ __align__(16) _Float16 As[2][128 * 32];
  __shared__ __align__(16) _Float16 Bs[2][128 * 32];
  const int swz = xcd_swz(blockIdx.x, 6 * 73);
  const int o0 = (swz % 6) * 128;
  const int m0 = (swz / 6) * 128;
  const int tid = threadIdx.x;
  const int lane = tid & 63, wave = tid >> 6;
  const int quad = lane >> 4, l16 = lane & 15;
  const int wm = wave & 1, wo = wave >> 1;

  const int row0 = wave * 32 + (lane >> 2);
  const int ch8  = (((lane & 3) ^ ((lane >> 3) & 3)) << 3);
  const int ar0 = min(m0 + row0, M_ROWS - 1);
  const int ar1 = min(m0 + row0 + 16, M_ROWS - 1);
  const int br0 = o0 + row0;
  const int br1 = o0 + row0 + 16;
  const int dl0 = wave * 1024 + lane * 8;
  const int dl1 = dl0 + 512;

  GLD16(A + (size_t)ar0 * CH + ch8, &As[0][dl0]);
  GLD16(A + (size_t)ar1 * CH + ch8, &As[0][dl1]);
  GLD16(W + (size_t)br0 * CH + ch8, &Bs[0][dl0]);
  GLD16(W + (size_t)br1 * CH + ch8, &Bs[0][dl1]);

  const int rdc = ((quad ^ ((l16 >> 1) & 3)) << 3);
  const int rdA = (wm * 64 + l16) * 32 + rdc;
  const int rdB = (wo * 64 + l16) * 32 + rdc;

  f32x4 acc[4][4] = {};
  int cur = 0;
  for (int ks = 0; ks < CH / 32; ++ks) {
    __syncthreads();
    if (ks + 1 < CH / 32) {
      const int kc = (ks + 1) * 32 + ch8;
      const int nb = cur ^ 1;
      GLD16(A + (size_t)ar0 * CH + kc, &As[nb][dl0]);
      GLD16(A + (size_t)ar1 * CH + kc, &As[nb][dl1]);
      GLD16(W + (size_t)br0 * CH + kc, &Bs[nb][dl0]);
      GLD16(W + (size_t)br1 * CH + kc, &Bs[nb][dl1]);
    }
    f16x8 af[4], bf_[4];
    #pragma unroll
    for (int i = 0; i < 4; ++i)
      af[i] = *(const f16x8*)&As[cur][rdA + i * 512];
    #pragma unroll
    for (int j = 0; j < 4; ++j)
      bf_[j] = *(const f16x8*)&Bs[cur][rdB + j * 512];
    #pragma unroll
    for (int i = 0; i < 4; ++i)
      #pragma unroll
      for (int j = 0; j < 4; ++j)
        acc[i][j] = MFMA16(af[i], bf_[j], acc[i][j]);
    cur ^= 1;
  }

  #pragma unroll
  for (int i = 0; i < 4; ++i) {
    #pragma unroll
    for (int rr = 0; rr < 4; ++rr) {
      int m = m0 + wm * 64 + i * 16 + quad * 4 + rr;
      if (m >= M_ROWS) continue;
      #pragma unroll
      for (int j = 0; j < 4; ++j) {
        int o = o0 + wo * 64 + j * 16 + l16;
        float val = acc[i][j][rr] + ldin(bias, o, f32);
        if (f32) ((float*)out)[(size_t)m * CH + o] = val;
        else ((__hip_bfloat16*)out)[(size_t)m * CH + o] = __float2bfloat16(val);
      }
    }
  }
}

extern "C" void kernel_launch(void* const* d_in, const int* in_sizes, int n_in,
                              void* d_out, int out_size, void* d_ws, size_t ws_size,
                              hipStream_t stream) {
  const void* x     = d_in[0];
  const void* Wqkv  = d_in[1];
  const void* Wproj = d_in[2];
  const void* bproj = d_in[3];
  const void* Wpre  = d_in[4];
  const void* Wpost = d_in[5];

  int* flag = (int*)d_ws;
  _Float16* ws = (_Float16*)((char*)d_ws + 16);
  const size_t QE  = (size_t)16 * NH * NTOK * HD;   // 7,090,176
  const size_t VTE = (size_t)16 * NH * HD * MPV;    // 7,864,320
  const size_t RPE = (size_t)16 * NH * 10 * NPAD;   // 1,136,640 f32
  const size_t EPB = (size_t)NH * NPAD * MPV;       // 4,546,560 f16 per batch

  _Float16* Xh  = ws;
  _Float16* Wqh = Xh + XHE;
  _Float16* Wph = Wqh + WQH;
  _Float16* q   = Wph + WPH;
  _Float16* k   = q + QE;
  _Float16* vT  = k + QE;
  _Float16* o1  = vT + VTE;
  float*    Rp  = (float*)(o1 + QE);

  // choose batch chunk from available workspace
  const size_t fixedB = 16 + ((size_t)XHE + WQH + WPH + 3 * QE + VTE)
                             * sizeof(_Float16) + RPE * sizeof(float);
  const size_t perB   = EPB * sizeof(_Float16);
  int cb = 16;
  while (cb > 1 && fixedB + (size_t)cb * perB > ws_size) cb >>= 1;

  _Float16* E = (_Float16*)(Rp + RPE);

  dim3 blk(256);
  hipLaunchKernelGGL(detect_dtype, dim3(1), blk, 0, stream,
                     (const unsigned short*)x, flag);
  hipLaunchKernelGGL(cvt_all, dim3((XHE + WQH + WPH) / 8 / 256 + 1), blk, 0,
                     stream, x, Wqkv, Wproj, Xh, flag);
  hipLaunchKernelGGL(gemm_qkv_mfma, dim3(18 * 73), blk, 0, stream,
                     Xh, Wqh, q, k, vT);
  hipLaunchKernelGGL(zerofill_vt, dim3(16 * NH * HD * 64 / 256), blk, 0, stream, vT);
  for (int b0 = 0; b0 < 16; b0 += cb) {
    hipLaunchKernelGGL(qk_exp, dim3(370 * cb), blk, 0, stream,
                       q, k, Wpre, flag, E, Rp, b0, cb);
    hipLaunchKernelGGL(pv_mix3, dim3(73 * cb), blk, 0, stream,
                       E, vT, Rp, Wpost, flag, o1, b0, cb);
  }
  hipLaunchKernelGGL(gemm_proj_mfma, dim3(6 * 73), blk, 0, stream,
                     o1, Wph, bproj, flag, d_out);
}

// Round 9
// 462.124 us; speedup vs baseline: 2.9099x; 1.1626x over previous
//
#include <hip/hip_runtime.h>
#include <hip/hip_bf16.h>

#define NTOK 577
#define CH 768
#define NH 12
#define HD 64
#define M_ROWS 9232      // B * N
#define NPAD 592         // n pitch of E
#define ESP 72           // qk_exp LDS E-tile pitch (f16): 144 B = 9*16 aligned
#define EST 18944        // E2 per-(g,mc) region: NPAD * 32

#define XHE 7090176      // M_ROWS * CH
#define WQH 1769472      // 3 * CH * CH
#define WPH 589824       // CH * CH

typedef _Float16 f16x8 __attribute__((ext_vector_type(8)));
typedef _Float16 f16x4 __attribute__((ext_vector_type(4)));
typedef _Float16 f16x2 __attribute__((ext_vector_type(2)));
typedef float f32x4 __attribute__((ext_vector_type(4)));

#define MFMA16(a, b, c) __builtin_amdgcn_mfma_f32_16x16x32_f16((a), (b), (c), 0, 0, 0)

// barrier that does NOT drain vmcnt (LDS deps need lgkmcnt only)
#define BAR() asm volatile("s_waitcnt lgkmcnt(0)\n\ts_barrier" ::: "memory")

// async global->LDS, 16 B per lane. LDS dest must be wave-linear (base+lane*16).
#define GLD16(gp, lp) __builtin_amdgcn_global_load_lds(               \
    (const __attribute__((address_space(1))) void*)(gp),              \
    (__attribute__((address_space(3))) void*)(lp), 16, 0, 0)

// XCD-chunked bijective swizzle (m204)
__device__ __forceinline__ int xcd_swz(int lin, int G) {
  int q = G >> 3, r = G & 7;
  int x = lin & 7, i = lin >> 3;
  return (x < r ? x * (q + 1) : r * (q + 1) + (x - r) * q) + i;
}

__device__ __forceinline__ float bf2f(unsigned int u16) {
  union { unsigned int i; float f; } x; x.i = u16 << 16; return x.f;
}

__device__ __forceinline__ float ldin(const void* p, size_t i, bool f32) {
  return f32 ? ((const float*)p)[i]
             : __bfloat162float(((const __hip_bfloat16*)p)[i]);
}

__device__ __forceinline__ f16x8 ld8_cvt(const void* p, size_t idx, bool f32) {
  f16x8 r;
  if (f32) {
    const float* f = (const float*)p + idx;
    const float4 u = *(const float4*)f;
    const float4 v = *(const float4*)(f + 4);
    r[0]=(_Float16)u.x; r[1]=(_Float16)u.y; r[2]=(_Float16)u.z; r[3]=(_Float16)u.w;
    r[4]=(_Float16)v.x; r[5]=(_Float16)v.y; r[6]=(_Float16)v.z; r[7]=(_Float16)v.w;
  } else {
    const unsigned short* s = (const unsigned short*)p + idx;
    uint4 u = *(const uint4*)s;
    unsigned int w0=u.x, w1=u.y, w2=u.z, w3=u.w;
    r[0]=(_Float16)bf2f(w0&0xffffu); r[1]=(_Float16)bf2f(w0>>16);
    r[2]=(_Float16)bf2f(w1&0xffffu); r[3]=(_Float16)bf2f(w1>>16);
    r[4]=(_Float16)bf2f(w2&0xffffu); r[5]=(_Float16)bf2f(w2>>16);
    r[6]=(_Float16)bf2f(w3&0xffffu); r[7]=(_Float16)bf2f(w3>>16);
  }
  return r;
}

// ---- Kernel 0: detect input dtype (fp32 vs bf16).
__global__ void detect_dtype(const unsigned short* __restrict__ xs,
                             int* __restrict__ flag) {
  __shared__ int cnt;
  if (threadIdx.x == 0) cnt = 0;
  __syncthreads();
  int local = 0;
  for (int i = threadIdx.x; i < 4096; i += 256) {
    unsigned int u = xs[2 * i];
    unsigned int e = (u >> 7) & 0xFFu;
    if (e >= 140u) local++;
  }
  atomicAdd(&cnt, local);
  __syncthreads();
  if (threadIdx.x == 0) *flag = (cnt > 100) ? 1 : 0;
}

// ---- Kernel 0b: convert x | Wqkv | Wproj into one contiguous f16 region.
__global__ __launch_bounds__(256) void cvt_all(
    const void* __restrict__ x, const void* __restrict__ wq,
    const void* __restrict__ wp, _Float16* __restrict__ dst,
    const int* __restrict__ flagp)
{
  const bool f32 = (*flagp != 0);
  size_t i = (size_t)(blockIdx.x * 256 + threadIdx.x) * 8;
  if (i >= (size_t)(XHE + WQH + WPH)) return;
  const void* src; size_t off;
  if (i < XHE)            { src = x;  off = i; }
  else if (i < XHE + WQH) { src = wq; off = i - XHE; }
  else                    { src = wp; off = i - XHE - WQH; }
  *(f16x8*)(dst + i) = ld8_cvt(src, off, f32);
}

// ---- Kernel 1: qkv = x @ Wqkv^T, m97 structure. vT is written M-TILED:
// vT2[b][g][mc=m/32][d 64][m%32] so pv's MFMA B-fragment read (lane row
// = d, col = m-granule) is a CONTIGUOUS 1 KB burst instead of 16 rows at
// 1280 B stride (round-8 PMC: 594 GB/s effective = transaction-split bound).
__global__ __launch_bounds__(256) void gemm_qkv_mfma(
    const _Float16* __restrict__ X, const _Float16* __restrict__ W,
    _Float16* __restrict__ q, _Float16* __restrict__ k,
    _Float16* __restrict__ vT)
{
  __shared__ __align__(16) _Float16 As[2][128 * 32];
  __shared__ __align__(16) _Float16 Bs[2][128 * 32];
  const int swz = xcd_swz(blockIdx.x, 18 * 73);
  const int bx = swz % 18;                 // output-col tile (fast: shares X)
  const int m0 = (swz / 18) * 128;
  const int tid = threadIdx.x;
  const int lane = tid & 63, wave = tid >> 6;
  const int quad = lane >> 4, l16 = lane & 15;
  const int wm = wave & 1, wo = wave >> 1;
  const int t = bx / 6;                    // 0=q 1=k 2=v
  const int o0 = bx * 128;
  const int o0loc = o0 - t * CH;

  const int row0 = wave * 32 + (lane >> 2);
  const int ch8  = (((lane & 3) ^ ((lane >> 3) & 3)) << 3);  // swizzled src col
  const int ar0 = min(m0 + row0, M_ROWS - 1);
  const int ar1 = min(m0 + row0 + 16, M_ROWS - 1);
  const int br0 = o0 + row0;
  const int br1 = o0 + row0 + 16;
  const int dl0 = wave * 1024 + lane * 8;   // linear LDS dest (f16 idx)
  const int dl1 = dl0 + 512;

  GLD16(X + (size_t)ar0 * CH + ch8, &As[0][dl0]);
  GLD16(X + (size_t)ar1 * CH + ch8, &As[0][dl1]);
  GLD16(W + (size_t)br0 * CH + ch8, &Bs[0][dl0]);
  GLD16(W + (size_t)br1 * CH + ch8, &Bs[0][dl1]);

  const int rdc = ((quad ^ ((l16 >> 1) & 3)) << 3);      // swizzled read col
  const int rdA = (wm * 64 + l16) * 32 + rdc;
  const int rdB = (wo * 64 + l16) * 32 + rdc;

  f32x4 acc[4][4] = {};
  int cur = 0;
  for (int ks = 0; ks < CH / 32; ++ks) {
    __syncthreads();                       // drains vmcnt: tile ks ready
    if (ks + 1 < CH / 32) {
      const int kc = (ks + 1) * 32 + ch8;
      const int nb = cur ^ 1;
      GLD16(X + (size_t)ar0 * CH + kc, &As[nb][dl0]);
      GLD16(X + (size_t)ar1 * CH + kc, &As[nb][dl1]);
      GLD16(W + (size_t)br0 * CH + kc, &Bs[nb][dl0]);
      GLD16(W + (size_t)br1 * CH + kc, &Bs[nb][dl1]);
    }
    f16x8 af[4], bf_[4];
    #pragma unroll
    for (int i = 0; i < 4; ++i)
      af[i] = *(const f16x8*)&As[cur][rdA + i * 512];
    #pragma unroll
    for (int j = 0; j < 4; ++j)
      bf_[j] = *(const f16x8*)&Bs[cur][rdB + j * 512];
    #pragma unroll
    for (int i = 0; i < 4; ++i)
      #pragma unroll
      for (int j = 0; j < 4; ++j)
        acc[i][j] = MFMA16(af[i], bf_[j], acc[i][j]);
    cur ^= 1;
  }

  if (t < 2) {
    #pragma unroll
    for (int i = 0; i < 4; ++i) {
      #pragma unroll
      for (int rr = 0; rr < 4; ++rr) {
        int m = m0 + wm * 64 + i * 16 + quad * 4 + rr;
        if (m >= M_ROWS) continue;
        int b = m / NTOK, n = m - b * NTOK;
        #pragma unroll
        for (int j = 0; j < 4; ++j) {
          int o = o0loc + wo * 64 + j * 16 + l16;
          int h = o >> 6, dd = o & 63;
          _Float16 val = (_Float16)acc[i][j][rr];
          if (t == 0)
            q[((size_t)(b * NH + h) * NTOK + n) * HD + dd] = val;
          else
            k[((size_t)(b * NH + h) * NTOK + n) * HD + dd] = val;
        }
      }
    }
  } else {
    // vT epilogue: per-wave LDS micro-transpose, then m-tiled store.
    __syncthreads();                       // LDS reads of K-loop done
    _Float16* scrb = &As[0][0] + wave * 512;
    #pragma unroll
    for (int i = 0; i < 4; ++i) {
      #pragma unroll
      for (int j = 0; j < 4; ++j) {
        _Float16* scr = scrb + (j & 1) * 256;
        f16x4 wv;
        wv[0] = (_Float16)acc[i][j][0]; wv[1] = (_Float16)acc[i][j][1];
        wv[2] = (_Float16)acc[i][j][2]; wv[3] = (_Float16)acc[i][j][3];
        *(f16x4*)&scr[l16 * 16 + quad * 4] = wv;   // scr[dd][n_loc]
        asm volatile("s_waitcnt lgkmcnt(0)" ::: "memory");
        f16x4 rv = *(const f16x4*)&scr[(lane >> 2) * 16 + (lane & 3) * 4];
        int oc = o0loc + wo * 64 + j * 16 + (lane >> 2);
        int hh = oc >> 6, ddg = oc & 63;
        int mbase = m0 + wm * 64 + i * 16 + (lane & 3) * 4;
        int bb = mbase / NTOK, nn2 = mbase - bb * NTOK;
        if (mbase + 3 < M_ROWS && nn2 + 3 < NTOK && !(nn2 & 1)
            && (nn2 & 31) <= 28) {
          _Float16* dst = &vT[((size_t)(bb * NH + hh) * 20 + (nn2 >> 5)) * 2048
                              + ddg * 32 + (nn2 & 31)];
          f16x2 lo2, hi2;
          lo2[0] = rv[0]; lo2[1] = rv[1];
          hi2[0] = rv[2]; hi2[1] = rv[3];
          *(f16x2*)dst = lo2;
          *(f16x2*)(dst + 2) = hi2;
        } else {
          #pragma unroll
          for (int e = 0; e < 4; ++e) {
            int m = mbase + e;
            if (m < M_ROWS) {
              int b2 = m / NTOK, n2 = m - b2 * NTOK;
              vT[((size_t)(b2 * NH + hh) * 20 + (n2 >> 5)) * 2048
                 + ddg * 32 + (n2 & 31)] = rv[e];
            }
          }
        }
      }
    }
  }
}

// ---- zero the m-pad of vT2 (m in [577,640)).
__global__ void zerofill_vt(_Float16* __restrict__ vT) {
  int idx = blockIdx.x * 256 + threadIdx.x;
  int r = idx >> 6, c = idx & 63;           // r = (b*NH+g)*64+d rows
  if (r < 16 * NH * HD && c < 63) {
    int m = NTOK + c;                       // 577..639
    int bg = r >> 6, d = r & 63;
    vT[((size_t)bg * 20 + (m >> 5)) * 2048 + d * 32 + (m & 31)] = (_Float16)0.f;
  }
}

// ---- Kernel 2: QK^T + Wpre mix + exp -> E2 (m-tiled) + partial rowsums.
// E2[bl][g][mc=m/32][n 592][m%32]: pv's fragment read (8 n-rows x 64 B)
// becomes a contiguous 512 B burst, and our store here is 1 KB-contiguous
// per wave (vs round-8's 128 B runs at 1280 B stride).
__global__ __launch_bounds__(256) void qk_exp(
    const _Float16* __restrict__ q, const _Float16* __restrict__ k,
    const void* __restrict__ Wpre, const int* __restrict__ flagp,
    _Float16* __restrict__ E, float* __restrict__ Rp, int b0, int cb)
{
  const bool f32 = (*flagp != 0);
  __shared__ float wp[NH * NH];
  __shared__ _Float16 Es[NH * 16 * ESP];   // [g][n(16)][m(64)], pitch 72
  const int tid = threadIdx.x;
  if (tid < NH * NH) wp[tid] = ldin(Wpre, tid, f32) * 0.125f;  // fold scale
  __syncthreads();
  const int swz = xcd_swz(blockIdx.x, 370 * cb);
  const int bl = swz / 370;
  const int ny = (swz % 370) / 10;
  const int bx = swz % 10;
  const int lane = tid & 63, wave = tid >> 6;
  const int quad = lane >> 4, l16 = lane & 15;
  const int b = b0 + bl;
  const int n0 = ny * 16;
  const int m0 = bx * 64 + wave * 16;
  const int nq = min(n0 + l16, NTOK - 1);
  const int mk = min(m0 + l16, NTOK - 1);
  const size_t qbase = ((size_t)b * NH * NTOK + nq) * HD + quad * 8;
  const size_t kbase = ((size_t)b * NH * NTOK + mk) * HD + quad * 8;
  f32x4 acc[NH];
  #pragma unroll
  for (int h = 0; h < NH; ++h) {
    const size_t ho = (size_t)h * NTOK * HD;
    f16x8 a0 = *(const f16x8*)(q + qbase + ho);
    f16x8 bb0 = *(const f16x8*)(k + kbase + ho);
    f16x8 a1 = *(const f16x8*)(q + qbase + ho + 32);
    f16x8 bb1 = *(const f16x8*)(k + kbase + ho + 32);
    f32x4 z = {0.f, 0.f, 0.f, 0.f};
    z = MFMA16(a0, bb0, z);
    acc[h] = MFMA16(a1, bb1, z);
  }
  const int mloc = wave * 16 + l16;          // col within 64-wide tile
  const bool valid = (m0 + l16 < NTOK);
  #pragma unroll
  for (int g = 0; g < NH; ++g) {
    float s0 = 0.f, s1 = 0.f, s2 = 0.f, s3 = 0.f;
    #pragma unroll
    for (int h = 0; h < NH; ++h) {
      float w = wp[g * NH + h];
      s0 += w * acc[h][0]; s1 += w * acc[h][1];
      s2 += w * acc[h][2]; s3 += w * acc[h][3];
    }
    Es[(g * 16 + quad * 4 + 0) * ESP + mloc] = (_Float16)(valid ? __expf(s0) : 0.f);
    Es[(g * 16 + quad * 4 + 1) * ESP + mloc] = (_Float16)(valid ? __expf(s1) : 0.f);
    Es[(g * 16 + quad * 4 + 2) * ESP + mloc] = (_Float16)(valid ? __expf(s2) : 0.f);
    Es[(g * 16 + quad * 4 + 3) * ESP + mloc] = (_Float16)(valid ? __expf(s3) : 0.f);
  }
  __syncthreads();
  // m-tiled store: 1536 granules of 16 B; per wave-iteration one (g,half)
  // region of 16 n-rows x 64 B = 1 KB contiguous.
  const int sub2 = tid & 3;
  const int nrow = (tid >> 2) & 15;
  const int rg0  = tid >> 6;                 // 0..3
  #pragma unroll
  for (int it = 0; it < 6; ++it) {
    int region = it * 4 + rg0;               // 0..23 = g*2+half
    int g = region >> 1, half = region & 1;
    f16x8 vv = *(const f16x8*)&Es[(g * 16 + nrow) * ESP + half * 32 + sub2 * 8];
    *(f16x8*)&E[((size_t)(bl * NH + g) * 20 + bx * 2 + half) * EST
                + (n0 + nrow) * 32 + sub2 * 8] = vv;
  }
  // partial rowsum of this block's 64 m-cols, per (g, n): Rp[b][g][bx][n]
  if (tid < NH * 16) {
    const _Float16* row = &Es[tid * ESP];
    float tot = 0.f;
    #pragma unroll
    for (int c = 0; c < 8; ++c) {
      f16x8 t = *(const f16x8*)&row[c * 8];
      #pragma unroll
      for (int j = 0; j < 8; ++j) tot += (float)t[j];
    }
    Rp[(((size_t)b * NH + (tid >> 4)) * 10 + bx) * NPAD + n0 + (tid & 15)] = tot;
  }
}

// ---- Kernel 3: pv_mix3 — 8-row n-tiles; E2/vT2 m-tiled reads (dense
// bursts). Same schedule as round 8 (BAR-prefetch double buffer, XOR-
// swizzled P2s, row-duplicated A, C rows n<8 stored).
__global__ __launch_bounds__(256) void pv_mix3(
    const _Float16* __restrict__ E, const _Float16* __restrict__ vT,
    const float* __restrict__ Rp, const void* __restrict__ Wpost,
    const int* __restrict__ flagp, _Float16* __restrict__ o1, int b0, int cb)
{
  const bool f32 = (*flagp != 0);
  __shared__ _Float16 P2s[NH * 8 * 128];    // [g][n8][m128], col ^ (n*8)
  __shared__ _Float16 w2s[NH * NH];
  __shared__ _Float16 rinvs[NH * 8];
  const int swz = xcd_swz(blockIdx.x, 73 * cb);
  const int bl = swz / 73;
  const int nx = swz % 73;
  const int tid = threadIdx.x;
  const int lane = tid & 63, w = tid >> 6;
  const int quad = lane >> 4, l16 = lane & 15;
  const int nn = l16 & 7;
  const int n0 = nx * 8;
  const int b = b0 + bl;
  if (tid < NH * NH) w2s[tid] = (_Float16)ldin(Wpost, tid, f32);
  if (tid < NH * 8) {
    float tot = 0.f;
    #pragma unroll
    for (int mb = 0; mb < 10; ++mb)
      tot += Rp[(((size_t)b * NH + (tid >> 3)) * 10 + mb) * NPAD + n0 + (tid & 7)];
    rinvs[tid] = (_Float16)(tot > 0.f ? 1.f / tot : 0.f);
  }
  __syncthreads();
  _Float16 rloc[NH];
  #pragma unroll
  for (int h = 0; h < NH; ++h) rloc[h] = rinvs[h * 8 + nn];

  f32x4 O[3][4];
  #pragma unroll
  for (int j = 0; j < 3; ++j)
    #pragma unroll
    for (int dt = 0; dt < 4; ++dt) O[j][dt] = (f32x4){0.f, 0.f, 0.f, 0.f};
  const int gg0 = w * 3;
  const int swzc = nn << 3;                 // column XOR for row nn

  // E2 fragment base: wave w mixes m-subchunk mc = i*4 + w (32 m).
  // lane addr = base + nn*32 + quad*8 -> contiguous 512 B per load.
  const size_t eoff = (size_t)(n0 + nn) * 32 + quad * 8;
  const size_t ehead = (size_t)20 * EST;    // per-head stride in E2
  const size_t ebl = (size_t)(bl * NH) * ehead;
  f16x8 ev0[NH], ev1[NH];
  #pragma unroll
  for (int h = 0; h < NH; ++h)
    ev0[h] = *(const f16x8*)&E[ebl + h * ehead + (size_t)w * EST + eoff];
  #pragma unroll
  for (int i = 0; i < 5; ++i) {
    f16x8* curp = (i & 1) ? ev1 : ev0;
    f16x8* nxtp = (i & 1) ? ev0 : ev1;
    BAR();                                  // previous P2s readers done
    if (i + 1 < 5) {                        // prefetch next m-chunk; stays
      #pragma unroll                        // in flight across both BARs
      for (int h = 0; h < NH; ++h)
        nxtp[h] = *(const f16x8*)&E[ebl + h * ehead
                                    + (size_t)((i + 1) * 4 + w) * EST + eoff];
    }
    #pragma unroll
    for (int h = 0; h < NH; ++h) curp[h] *= rloc[h];
    #pragma unroll
    for (int gp = 0; gp < NH; ++gp) {
      f16x8 p = curp[0] * w2s[gp * NH + 0];
      #pragma unroll
      for (int h = 1; h < NH; ++h) p += curp[h] * w2s[gp * NH + h];
      if (l16 < 8)                          // lanes 8-15 hold duplicate data
        *(f16x8*)&P2s[gp * 1024 + nn * 128 + ((w * 32 + quad * 8) ^ swzc)] = p;
    }
    BAR();
    #pragma unroll
    for (int kc = 0; kc < 4; ++kc) {
      #pragma unroll
      for (int j = 0; j < 3; ++j) {
        const int g = gg0 + j;
        f16x8 a = *(const f16x8*)&P2s[g * 1024 + nn * 128
                                      + ((kc * 32 + quad * 8) ^ swzc)];
        #pragma unroll
        for (int dt = 0; dt < 4; ++dt) {
          // vT2: contiguous 1 KB per (g, mc, dt) fragment load
          f16x8 bv = *(const f16x8*)(
              vT + ((size_t)(b * NH + g) * 20 + i * 4 + kc) * 2048
                 + (dt * 16 + l16) * 32 + quad * 8);
          O[j][dt] = MFMA16(a, bv, O[j][dt]);   // C rows 8-15 = dup of 0-7
        }
      }
    }
  }
  #pragma unroll
  for (int j = 0; j < 3; ++j)
    #pragma unroll
    for (int dt = 0; dt < 4; ++dt)
      #pragma unroll
      for (int r = 0; r < 4; ++r) {
        int n = quad * 4 + r;               // only quad<2 rows are real
        if (n < 8 && n0 + n < NTOK)
          o1[((size_t)b * NTOK + n0 + n) * CH + (gg0 + j) * HD + dt * 16 + l16] =
              (_Float16)O[j][dt][r];
      }
}

// ---- Kernel 4: out = o1 @ Wproj^T + bproj, m97-style staging.
__global__ __launch_bounds__(256) void gemm_proj_mfma(
    const _Float16* __restrict__ A, const _Float16* __restrict__ W,
    const void* __restrict__ bias, const int* __restrict__ flagp,
    void* __restrict__ out)
{
  const bool f32 = (*flagp != 0);
  __shared__ __align__(16) _Float16 As[2][128 * 32];
  __shared__ __align__(16) _Float16 Bs[2][128 * 32];
  const int swz = xcd_swz(blockIdx.x, 6 * 73);
  const int o0 = (swz % 6) * 128;
  const int m0 = (swz / 6) * 128;
  const int tid = threadIdx.x;
  const int lane = tid & 63, wave = tid >> 6;
  const int quad = lane >> 4, l16 = lane & 15;
  const int wm = wave & 1, wo = wave >> 1;

  const int row0 = wave * 32 + (lane >> 2);
  const int ch8  = (((lane & 3) ^ ((lane >> 3) & 3)) << 3);
  const int ar0 = min(m0 + row0, M_ROWS - 1);
  const int ar1 = min(m0 + row0 + 16, M_ROWS - 1);
  const int br0 = o0 + row0;
  const int br1 = o0 + row0 + 16;
  const int dl0 = wave * 1024 + lane * 8;
  const int dl1 = dl0 + 512;

  GLD16(A + (size_t)ar0 * CH + ch8, &As[0][dl0]);
  GLD16(A + (size_t)ar1 * CH + ch8, &As[0][dl1]);
  GLD16(W + (size_t)br0 * CH + ch8, &Bs[0][dl0]);
  GLD16(W + (size_t)br1 * CH + ch8, &Bs[0][dl1]);

  const int rdc = ((quad ^ ((l16 >> 1) & 3)) << 3);
  const int rdA = (wm * 64 + l16) * 32 + rdc;
  const int rdB = (wo * 64 + l16) * 32 + rdc;

  f32x4 acc[4][4] = {};
  int cur = 0;
  for (int ks = 0; ks < CH / 32; ++ks) {
    __syncthreads();
    if (ks + 1 < CH / 32) {
      const int kc = (ks + 1) * 32 + ch8;
      const int nb = cur ^ 1;
      GLD16(A + (size_t)ar0 * CH + kc, &As[nb][dl0]);
      GLD16(A + (size_t)ar1 * CH + kc, &As[nb][dl1]);
      GLD16(W + (size_t)br0 * CH + kc, &Bs[nb][dl0]);
      GLD16(W + (size_t)br1 * CH + kc, &Bs[nb][dl1]);
    }
    f16x8 af[4], bf_[4];
    #pragma unroll
    for (int i = 0; i < 4; ++i)
      af[i] = *(const f16x8*)&As[cur][rdA + i * 512];
    #pragma unroll
    for (int j = 0; j < 4; ++j)
      bf_[j] = *(const f16x8*)&Bs[cur][rdB + j * 512];
    #pragma unroll
    for (int i = 0; i < 4; ++i)
      #pragma unroll
      for (int j = 0; j < 4; ++j)
        acc[i][j] = MFMA16(af[i], bf_[j], acc[i][j]);
    cur ^= 1;
  }

  #pragma unroll
  for (int i = 0; i < 4; ++i) {
    #pragma unroll
    for (int rr = 0; rr < 4; ++rr) {
      int m = m0 + wm * 64 + i * 16 + quad * 4 + rr;
      if (m >= M_ROWS) continue;
      #pragma unroll
      for (int j = 0; j < 4; ++j) {
        int o = o0 + wo * 64 + j * 16 + l16;
        float val = acc[i][j][rr] + ldin(bias, o, f32);
        if (f32) ((float*)out)[(size_t)m * CH + o] = val;
        else ((__hip_bfloat16*)out)[(size_t)m * CH + o] = __float2bfloat16(val);
      }
    }
  }
}

extern "C" void kernel_launch(void* const* d_in, const int* in_sizes, int n_in,
                              void* d_out, int out_size, void* d_ws, size_t ws_size,
                              hipStream_t stream) {
  const void* x     = d_in[0];
  const void* Wqkv  = d_in[1];
  const void* Wproj = d_in[2];
  const void* bproj = d_in[3];
  const void* Wpre  = d_in[4];
  const void* Wpost = d_in[5];

  int* flag = (int*)d_ws;
  _Float16* ws = (_Float16*)((char*)d_ws + 16);
  const size_t QE  = (size_t)16 * NH * NTOK * HD;   // 7,090,176
  const size_t VTE = (size_t)16 * NH * 20 * 2048;   // 7,864,320 (m-tiled)
  const size_t RPE = (size_t)16 * NH * 10 * NPAD;   // 1,136,640 f32
  const size_t EPB = (size_t)NH * 20 * EST;         // 4,546,560 f16 per batch

  _Float16* Xh  = ws;
  _Float16* Wqh = Xh + XHE;
  _Float16* Wph = Wqh + WQH;
  _Float16* q   = Wph + WPH;
  _Float16* k   = q + QE;
  _Float16* vT  = k + QE;
  _Float16* o1  = vT + VTE;
  float*    Rp  = (float*)(o1 + QE);

  // choose batch chunk from available workspace
  const size_t fixedB = 16 + ((size_t)XHE + WQH + WPH + 3 * QE + VTE)
                             * sizeof(_Float16) + RPE * sizeof(float);
  const size_t perB   = EPB * sizeof(_Float16);
  int cb = 16;
  while (cb > 1 && fixedB + (size_t)cb * perB > ws_size) cb >>= 1;

  _Float16* E = (_Float16*)(Rp + RPE);

  dim3 blk(256);
  hipLaunchKernelGGL(detect_dtype, dim3(1), blk, 0, stream,
                     (const unsigned short*)x, flag);
  hipLaunchKernelGGL(cvt_all, dim3((XHE + WQH + WPH) / 8 / 256 + 1), blk, 0,
                     stream, x, Wqkv, Wproj, Xh, flag);
  hipLaunchKernelGGL(gemm_qkv_mfma, dim3(18 * 73), blk, 0, stream,
                     Xh, Wqh, q, k, vT);
  hipLaunchKernelGGL(zerofill_vt, dim3(16 * NH * HD * 64 / 256), blk, 0, stream, vT);
  for (int b0 = 0; b0 < 16; b0 += cb) {
    hipLaunchKernelGGL(qk_exp, dim3(370 * cb), blk, 0, stream,
                       q, k, Wpre, flag, E, Rp, b0, cb);
    hipLaunchKernelGGL(pv_mix3, dim3(73 * cb), blk, 0, stream,
                       E, vT, Rp, Wpost, flag, o1, b0, cb);
  }
  hipLaunchKernelGGL(gemm_proj_mfma, dim3(6 * 73), blk, 0, stream,
                     o1, Wph, bproj, flag, d_out);
}

// Round 11
// 396.342 us; speedup vs baseline: 3.3929x; 1.1660x over previous
//
#include <hip/hip_runtime.h>
#include <hip/hip_bf16.h>

#define NTOK 577
#define CH 768
#define NH 12
#define HD 64
#define M_ROWS 9232      // B * N
#define NPAD 592         // n pitch of E / Rp
#define ESP 72           // qk_exp LDS E-tile pitch (f16): 144 B = 9*16 aligned
#define EST 18944        // E2 per-(g,mc) region: NPAD * 32

#define XHE 7090176      // M_ROWS * CH
#define WQH 1769472      // 3 * CH * CH
#define WPH 589824       // CH * CH

typedef _Float16 f16x8 __attribute__((ext_vector_type(8)));
typedef _Float16 f16x4 __attribute__((ext_vector_type(4)));
typedef _Float16 f16x2 __attribute__((ext_vector_type(2)));
typedef float f32x4 __attribute__((ext_vector_type(4)));

#define MFMA16(a, b, c) __builtin_amdgcn_mfma_f32_16x16x32_f16((a), (b), (c), 0, 0, 0)

// barrier that does NOT drain vmcnt (LDS deps need lgkmcnt only)
#define BAR() asm volatile("s_waitcnt lgkmcnt(0)\n\ts_barrier" ::: "memory")

// async global->LDS, 16 B per lane. LDS dest must be wave-linear (base+lane*16).
#define GLD16(gp, lp) __builtin_amdgcn_global_load_lds(               \
    (const __attribute__((address_space(1))) void*)(gp),              \
    (__attribute__((address_space(3))) void*)(lp), 16, 0, 0)

// XCD-chunked bijective swizzle (m204)
__device__ __forceinline__ int xcd_swz(int lin, int G) {
  int q = G >> 3, r = G & 7;
  int x = lin & 7, i = lin >> 3;
  return (x < r ? x * (q + 1) : r * (q + 1) + (x - r) * q) + i;
}

__device__ __forceinline__ float bf2f(unsigned int u16) {
  union { unsigned int i; float f; } x; x.i = u16 << 16; return x.f;
}

__device__ __forceinline__ float ldin(const void* p, size_t i, bool f32) {
  return f32 ? ((const float*)p)[i]
             : __bfloat162float(((const __hip_bfloat16*)p)[i]);
}

__device__ __forceinline__ f16x8 ld8_cvt(const void* p, size_t idx, bool f32) {
  f16x8 r;
  if (f32) {
    const float* f = (const float*)p + idx;
    const float4 u = *(const float4*)f;
    const float4 v = *(const float4*)(f + 4);
    r[0]=(_Float16)u.x; r[1]=(_Float16)u.y; r[2]=(_Float16)u.z; r[3]=(_Float16)u.w;
    r[4]=(_Float16)v.x; r[5]=(_Float16)v.y; r[6]=(_Float16)v.z; r[7]=(_Float16)v.w;
  } else {
    const unsigned short* s = (const unsigned short*)p + idx;
    uint4 u = *(const uint4*)s;
    unsigned int w0=u.x, w1=u.y, w2=u.z, w3=u.w;
    r[0]=(_Float16)bf2f(w0&0xffffu); r[1]=(_Float16)bf2f(w0>>16);
    r[2]=(_Float16)bf2f(w1&0xffffu); r[3]=(_Float16)bf2f(w1>>16);
    r[4]=(_Float16)bf2f(w2&0xffffu); r[5]=(_Float16)bf2f(w2>>16);
    r[6]=(_Float16)bf2f(w3&0xffffu); r[7]=(_Float16)bf2f(w3>>16);
  }
  return r;
}

// ---- Kernel 0: detect input dtype (fp32 vs bf16).
__global__ void detect_dtype(const unsigned short* __restrict__ xs,
                             int* __restrict__ flag) {
  __shared__ int cnt;
  if (threadIdx.x == 0) cnt = 0;
  __syncthreads();
  int local = 0;
  for (int i = threadIdx.x; i < 4096; i += 256) {
    unsigned int u = xs[2 * i];
    unsigned int e = (u >> 7) & 0xFFu;
    if (e >= 140u) local++;
  }
  atomicAdd(&cnt, local);
  __syncthreads();
  if (threadIdx.x == 0) *flag = (cnt > 100) ? 1 : 0;
}

// ---- Kernel 0b: convert x | Wqkv | Wproj into one contiguous f16 region.
__global__ __launch_bounds__(256) void cvt_all(
    const void* __restrict__ x, const void* __restrict__ wq,
    const void* __restrict__ wp, _Float16* __restrict__ dst,
    const int* __restrict__ flagp)
{
  const bool f32 = (*flagp != 0);
  size_t i = (size_t)(blockIdx.x * 256 + threadIdx.x) * 8;
  if (i >= (size_t)(XHE + WQH + WPH)) return;
  const void* src; size_t off;
  if (i < XHE)            { src = x;  off = i; }
  else if (i < XHE + WQH) { src = wq; off = i - XHE; }
  else                    { src = wp; off = i - XHE - WQH; }
  *(f16x8*)(dst + i) = ld8_cvt(src, off, f32);
}

// ---- Kernel 1: qkv = x @ Wqkv^T, m97 structure. ALL outputs fragment/
// m-tiled:
//   qF[b][h][nt=n/16][dc=d/8][n%16][8]  (37 tiles)  — qk_exp A-frag read
//   kF[b][h][mt=m/16][dc][m%16][8]      (40 tiles)  — qk_exp B-frag read
//   vT2[b][g][mc=m/32][d 64][m%32]      (20 tiles)  — pv B-frag read
// so every consumer MFMA fragment load is a contiguous burst. Fragment a0
// (d 0..31) sits at tile_base + lane*8; a1 (d 32..63) at +512 (dc 4..7).
// (Round-10 bug: a1 read at +1024 = next token-tile -> absmax 0.031.)
__global__ __launch_bounds__(256) void gemm_qkv_mfma(
    const _Float16* __restrict__ X, const _Float16* __restrict__ W,
    _Float16* __restrict__ q, _Float16* __restrict__ k,
    _Float16* __restrict__ vT)
{
  __shared__ __align__(16) _Float16 As[2][128 * 32];
  __shared__ __align__(16) _Float16 Bs[2][128 * 32];
  const int swz = xcd_swz(blockIdx.x, 18 * 73);
  const int bx = swz % 18;                 // output-col tile (fast: shares X)
  const int m0 = (swz / 18) * 128;
  const int tid = threadIdx.x;
  const int lane = tid & 63, wave = tid >> 6;
  const int quad = lane >> 4, l16 = lane & 15;
  const int wm = wave & 1, wo = wave >> 1;
  const int t = bx / 6;                    // 0=q 1=k 2=v
  const int o0 = bx * 128;
  const int o0loc = o0 - t * CH;

  const int row0 = wave * 32 + (lane >> 2);
  const int ch8  = (((lane & 3) ^ ((lane >> 3) & 3)) << 3);  // swizzled src col
  const int ar0 = min(m0 + row0, M_ROWS - 1);
  const int ar1 = min(m0 + row0 + 16, M_ROWS - 1);
  const int br0 = o0 + row0;
  const int br1 = o0 + row0 + 16;
  const int dl0 = wave * 1024 + lane * 8;   // linear LDS dest (f16 idx)
  const int dl1 = dl0 + 512;

  GLD16(X + (size_t)ar0 * CH + ch8, &As[0][dl0]);
  GLD16(X + (size_t)ar1 * CH + ch8, &As[0][dl1]);
  GLD16(W + (size_t)br0 * CH + ch8, &Bs[0][dl0]);
  GLD16(W + (size_t)br1 * CH + ch8, &Bs[0][dl1]);

  const int rdc = ((quad ^ ((l16 >> 1) & 3)) << 3);      // swizzled read col
  const int rdA = (wm * 64 + l16) * 32 + rdc;
  const int rdB = (wo * 64 + l16) * 32 + rdc;

  f32x4 acc[4][4] = {};
  int cur = 0;
  for (int ks = 0; ks < CH / 32; ++ks) {
    __syncthreads();                       // drains vmcnt: tile ks ready
    if (ks + 1 < CH / 32) {
      const int kc = (ks + 1) * 32 + ch8;
      const int nb = cur ^ 1;
      GLD16(X + (size_t)ar0 * CH + kc, &As[nb][dl0]);
      GLD16(X + (size_t)ar1 * CH + kc, &As[nb][dl1]);
      GLD16(W + (size_t)br0 * CH + kc, &Bs[nb][dl0]);
      GLD16(W + (size_t)br1 * CH + kc, &Bs[nb][dl1]);
    }
    f16x8 af[4], bf_[4];
    #pragma unroll
    for (int i = 0; i < 4; ++i)
      af[i] = *(const f16x8*)&As[cur][rdA + i * 512];
    #pragma unroll
    for (int j = 0; j < 4; ++j)
      bf_[j] = *(const f16x8*)&Bs[cur][rdB + j * 512];
    #pragma unroll
    for (int i = 0; i < 4; ++i)
      #pragma unroll
      for (int j = 0; j < 4; ++j)
        acc[i][j] = MFMA16(af[i], bf_[j], acc[i][j]);
    cur ^= 1;
  }

  if (t < 2) {
    _Float16* dbuf = (t == 0) ? q : k;
    const int ntl = (t == 0) ? 37 : 40;
    #pragma unroll
    for (int i = 0; i < 4; ++i) {
      #pragma unroll
      for (int rr = 0; rr < 4; ++rr) {
        int m = m0 + wm * 64 + i * 16 + quad * 4 + rr;
        if (m >= M_ROWS) continue;
        int b = m / NTOK, n = m - b * NTOK;
        #pragma unroll
        for (int j = 0; j < 4; ++j) {
          int o = o0loc + wo * 64 + j * 16 + l16;
          int h = o >> 6, dd = o & 63;
          dbuf[((size_t)(b * NH + h) * ntl + (n >> 4)) * 1024
               + (dd >> 3) * 128 + (n & 15) * 8 + (dd & 7)] =
              (_Float16)acc[i][j][rr];
        }
      }
    }
  } else {
    // vT epilogue: per-wave LDS micro-transpose, then m-tiled store.
    __syncthreads();                       // LDS reads of K-loop done
    _Float16* scrb = &As[0][0] + wave * 512;
    #pragma unroll
    for (int i = 0; i < 4; ++i) {
      #pragma unroll
      for (int j = 0; j < 4; ++j) {
        _Float16* scr = scrb + (j & 1) * 256;
        f16x4 wv;
        wv[0] = (_Float16)acc[i][j][0]; wv[1] = (_Float16)acc[i][j][1];
        wv[2] = (_Float16)acc[i][j][2]; wv[3] = (_Float16)acc[i][j][3];
        *(f16x4*)&scr[l16 * 16 + quad * 4] = wv;   // scr[dd][n_loc]
        asm volatile("s_waitcnt lgkmcnt(0)" ::: "memory");
        f16x4 rv = *(const f16x4*)&scr[(lane >> 2) * 16 + (lane & 3) * 4];
        int oc = o0loc + wo * 64 + j * 16 + (lane >> 2);
        int hh = oc >> 6, ddg = oc & 63;
        int mbase = m0 + wm * 64 + i * 16 + (lane & 3) * 4;
        int bb = mbase / NTOK, nn2 = mbase - bb * NTOK;
        if (mbase + 3 < M_ROWS && nn2 + 3 < NTOK && !(nn2 & 1)
            && (nn2 & 31) <= 28) {
          _Float16* dst = &vT[((size_t)(bb * NH + hh) * 20 + (nn2 >> 5)) * 2048
                              + ddg * 32 + (nn2 & 31)];
          f16x2 lo2, hi2;
          lo2[0] = rv[0]; lo2[1] = rv[1];
          hi2[0] = rv[2]; hi2[1] = rv[3];
          *(f16x2*)dst = lo2;
          *(f16x2*)(dst + 2) = hi2;
        } else {
          #pragma unroll
          for (int e = 0; e < 4; ++e) {
            int m = mbase + e;
            if (m < M_ROWS) {
              int b2 = m / NTOK, n2 = m - b2 * NTOK;
              vT[((size_t)(b2 * NH + hh) * 20 + (n2 >> 5)) * 2048
                 + ddg * 32 + (n2 & 31)] = rv[e];
            }
          }
        }
      }
    }
  }
}

// ---- zero all pads: vT2 m in [577,640), kF m in [577,640), qF n in [577,592)
__global__ void zerofill_pads(_Float16* __restrict__ vT,
                              _Float16* __restrict__ qF,
                              _Float16* __restrict__ kF) {
  const int NV = 16 * NH * HD * 63;        // 774,144
  const int NK = 16 * NH * 63 * 64;        // 774,144
  const int NQ = 16 * NH * 15 * 64;        // 184,320
  int idx = blockIdx.x * 256 + threadIdx.x;
  if (idx < NV) {
    int r = idx / 63, c = idx % 63;        // r = bg*64+d
    int m = NTOK + c;
    int bg = r >> 6, d = r & 63;
    vT[((size_t)bg * 20 + (m >> 5)) * 2048 + d * 32 + (m & 31)] = (_Float16)0.f;
  } else if (idx < NV + NK) {
    int u = idx - NV;
    int bh = u / (63 * 64), v = u % (63 * 64);
    int m = NTOK + v / 64, d = v % 64;
    kF[((size_t)bh * 40 + (m >> 4)) * 1024
       + (d >> 3) * 128 + (m & 15) * 8 + (d & 7)] = (_Float16)0.f;
  } else if (idx < NV + NK + NQ) {
    int u = idx - NV - NK;
    int bh = u / (15 * 64), v = u % (15 * 64);
    int n = NTOK + v / 64, d = v % 64;
    qF[((size_t)bh * 37 + (n >> 4)) * 1024
       + (d >> 3) * 128 + (n & 15) * 8 + (d & 7)] = (_Float16)0.f;
  }
}

// ---- Kernel 2: QK^T + Wpre mix + exp -> E2 (m-tiled) + partial rowsums.
// q/k fragment-linear: a0/b0 at tile_base + lane*8 (d 0..31), a1/b1 at
// +512 (d 32..63). Pad rows zeroed -> no clamps.
__global__ __launch_bounds__(256) void qk_exp(
    const _Float16* __restrict__ q, const _Float16* __restrict__ k,
    const void* __restrict__ Wpre, const int* __restrict__ flagp,
    _Float16* __restrict__ E, float* __restrict__ Rp, int b0, int cb)
{
  const bool f32 = (*flagp != 0);
  __shared__ float wp[NH * NH];
  __shared__ _Float16 Es[NH * 16 * ESP];   // [g][n(16)][m(64)], pitch 72
  const int tid = threadIdx.x;
  if (tid < NH * NH) wp[tid] = ldin(Wpre, tid, f32) * 0.125f;  // fold scale
  __syncthreads();
  const int swz = xcd_swz(blockIdx.x, 370 * cb);
  const int bl = swz / 370;
  const int ny = (swz % 370) / 10;
  const int bx = swz % 10;
  const int lane = tid & 63, wave = tid >> 6;
  const int quad = lane >> 4, l16 = lane & 15;
  const int b = b0 + bl;
  const int n0 = ny * 16;
  const int m0 = bx * 64 + wave * 16;
  const _Float16* qp0 = q + ((size_t)(b * NH) * 37 + ny) * 1024 + lane * 8;
  const _Float16* kp0 = k + ((size_t)(b * NH) * 40 + bx * 4 + wave) * 1024
                          + lane * 8;
  f32x4 acc[NH];
  #pragma unroll
  for (int h = 0; h < NH; ++h) {
    const _Float16* qp = qp0 + (size_t)h * (37 * 1024);
    const _Float16* kp = kp0 + (size_t)h * (40 * 1024);
    f16x8 a0 = *(const f16x8*)qp;
    f16x8 bb0 = *(const f16x8*)kp;
    f16x8 a1 = *(const f16x8*)(qp + 512);
    f16x8 bb1 = *(const f16x8*)(kp + 512);
    f32x4 z = {0.f, 0.f, 0.f, 0.f};
    z = MFMA16(a0, bb0, z);
    acc[h] = MFMA16(a1, bb1, z);
  }
  const int mloc = wave * 16 + l16;          // col within 64-wide tile
  const bool valid = (m0 + l16 < NTOK);      // pad m -> exp=1 must be masked
  #pragma unroll
  for (int g = 0; g < NH; ++g) {
    float s0 = 0.f, s1 = 0.f, s2 = 0.f, s3 = 0.f;
    #pragma unroll
    for (int h = 0; h < NH; ++h) {
      float w = wp[g * NH + h];
      s0 += w * acc[h][0]; s1 += w * acc[h][1];
      s2 += w * acc[h][2]; s3 += w * acc[h][3];
    }
    Es[(g * 16 + quad * 4 + 0) * ESP + mloc] = (_Float16)(valid ? __expf(s0) : 0.f);
    Es[(g * 16 + quad * 4 + 1) * ESP + mloc] = (_Float16)(valid ? __expf(s1) : 0.f);
    Es[(g * 16 + quad * 4 + 2) * ESP + mloc] = (_Float16)(valid ? __expf(s2) : 0.f);
    Es[(g * 16 + quad * 4 + 3) * ESP + mloc] = (_Float16)(valid ? __expf(s3) : 0.f);
  }
  __syncthreads();
  // m-tiled store: per wave-iteration one (g,half) region of 16 n-rows x
  // 64 B = 1 KB contiguous.
  const int sub2 = tid & 3;
  const int nrow = (tid >> 2) & 15;
  const int rg0  = tid >> 6;                 // 0..3
  #pragma unroll
  for (int it = 0; it < 6; ++it) {
    int region = it * 4 + rg0;               // 0..23 = g*2+half
    int g = region >> 1, half = region & 1;
    f16x8 vv = *(const f16x8*)&Es[(g * 16 + nrow) * ESP + half * 32 + sub2 * 8];
    *(f16x8*)&E[((size_t)(bl * NH + g) * 20 + bx * 2 + half) * EST
                + (n0 + nrow) * 32 + sub2 * 8] = vv;
  }
  // partial rowsum of this block's 64 m-cols, per (g, n): Rp[b][g][bx][n]
  if (tid < NH * 16) {
    const _Float16* row = &Es[tid * ESP];
    float tot = 0.f;
    #pragma unroll
    for (int c = 0; c < 8; ++c) {
      f16x8 t = *(const f16x8*)&row[c * 8];
      #pragma unroll
      for (int j = 0; j < 8; ++j) tot += (float)t[j];
    }
    Rp[(((size_t)b * NH + (tid >> 4)) * 10 + bx) * NPAD + n0 + (tid & 15)] = tot;
  }
}

// ---- Kernel 3: pv_mix3 — 8-row n-tiles; E2/vT2 m-tiled reads (dense
// bursts). BAR-prefetch double buffer, XOR-swizzled P2s, row-duplicated A.
__global__ __launch_bounds__(256) void pv_mix3(
    const _Float16* __restrict__ E, const _Float16* __restrict__ vT,
    const float* __restrict__ Rp, const void* __restrict__ Wpost,
    const int* __restrict__ flagp, _Float16* __restrict__ o1, int b0, int cb)
{
  const bool f32 = (*flagp != 0);
  __shared__ _Float16 P2s[NH * 8 * 128];    // [g][n8][m128], col ^ (n*8)
  __shared__ _Float16 w2s[NH * NH];
  __shared__ _Float16 rinvs[NH * 8];
  const int swz = xcd_swz(blockIdx.x, 73 * cb);
  const int bl = swz / 73;
  const int nx = swz % 73;
  const int tid = threadIdx.x;
  const int lane = tid & 63, w = tid >> 6;
  const int quad = lane >> 4, l16 = lane & 15;
  const int nn = l16 & 7;
  const int n0 = nx * 8;
  const int b = b0 + bl;
  if (tid < NH * NH) w2s[tid] = (_Float16)ldin(Wpost, tid, f32);
  if (tid < NH * 8) {
    float tot = 0.f;
    #pragma unroll
    for (int mb = 0; mb < 10; ++mb)
      tot += Rp[(((size_t)b * NH + (tid >> 3)) * 10 + mb) * NPAD + n0 + (tid & 7)];
    rinvs[tid] = (_Float16)(tot > 0.f ? 1.f / tot : 0.f);
  }
  __syncthreads();
  _Float16 rloc[NH];
  #pragma unroll
  for (int h = 0; h < NH; ++h) rloc[h] = rinvs[h * 8 + nn];

  f32x4 O[3][4];
  #pragma unroll
  for (int j = 0; j < 3; ++j)
    #pragma unroll
    for (int dt = 0; dt < 4; ++dt) O[j][dt] = (f32x4){0.f, 0.f, 0.f, 0.f};
  const int gg0 = w * 3;
  const int swzc = nn << 3;                 // column XOR for row nn

  const size_t eoff = (size_t)(n0 + nn) * 32 + quad * 8;
  const size_t ehead = (size_t)20 * EST;    // per-head stride in E2
  const size_t ebl = (size_t)(bl * NH) * ehead;
  f16x8 ev0[NH], ev1[NH];
  #pragma unroll
  for (int h = 0; h < NH; ++h)
    ev0[h] = *(const f16x8*)&E[ebl + h * ehead + (size_t)w * EST + eoff];
  #pragma unroll
  for (int i = 0; i < 5; ++i) {
    f16x8* curp = (i & 1) ? ev1 : ev0;
    f16x8* nxtp = (i & 1) ? ev0 : ev1;
    BAR();                                  // previous P2s readers done
    if (i + 1 < 5) {                        // prefetch next m-chunk; stays
      #pragma unroll                        // in flight across both BARs
      for (int h = 0; h < NH; ++h)
        nxtp[h] = *(const f16x8*)&E[ebl + h * ehead
                                    + (size_t)((i + 1) * 4 + w) * EST + eoff];
    }
    #pragma unroll
    for (int h = 0; h < NH; ++h) curp[h] *= rloc[h];
    #pragma unroll
    for (int gp = 0; gp < NH; ++gp) {
      f16x8 p = curp[0] * w2s[gp * NH + 0];
      #pragma unroll
      for (int h = 1; h < NH; ++h) p += curp[h] * w2s[gp * NH + h];
      if (l16 < 8)                          // lanes 8-15 hold duplicate data
        *(f16x8*)&P2s[gp * 1024 + nn * 128 + ((w * 32 + quad * 8) ^ swzc)] = p;
    }
    BAR();
    #pragma unroll
    for (int kc = 0; kc < 4; ++kc) {
      #pragma unroll
      for (int j = 0; j < 3; ++j) {
        const int g = gg0 + j;
        f16x8 a = *(const f16x8*)&P2s[g * 1024 + nn * 128
                                      + ((kc * 32 + quad * 8) ^ swzc)];
        #pragma unroll
        for (int dt = 0; dt < 4; ++dt) {
          // vT2: contiguous 1 KB per (g, mc, dt) fragment load
          f16x8 bv = *(const f16x8*)(
              vT + ((size_t)(b * NH + g) * 20 + i * 4 + kc) * 2048
                 + (dt * 16 + l16) * 32 + quad * 8);
          O[j][dt] = MFMA16(a, bv, O[j][dt]);   // C rows 8-15 = dup of 0-7
        }
      }
    }
  }
  #pragma unroll
  for (int j = 0; j < 3; ++j)
    #pragma unroll
    for (int dt = 0; dt < 4; ++dt)
      #pragma unroll
      for (int r = 0; r < 4; ++r) {
        int n = quad * 4 + r;               // only quad<2 rows are real
        if (n < 8 && n0 + n < NTOK)
          o1[((size_t)b * NTOK + n0 + n) * CH + (gg0 + j) * HD + dt * 16 + l16] =
              (_Float16)O[j][dt][r];
      }
}

// ---- Kernel 4: out = o1 @ Wproj^T + bproj, m97-style staging.
__global__ __launch_bounds__(256) void gemm_proj_mfma(
    const _Float16* __restrict__ A, const _Float16* __restrict__ W,
    const void* __restrict__ bias, const int* __restrict__ flagp,
    void* __restrict__ out)
{
  const bool f32 = (*flagp != 0);
  __shared__ __align__(16) _Float16 As[2][128 * 32];
  __shared__ __align__(16) _Float16 Bs[2][128 * 32];
  const int swz = xcd_swz(blockIdx.x, 6 * 73);
  const int o0 = (swz % 6) * 128;
  const int m0 = (swz / 6) * 128;
  const int tid = threadIdx.x;
  const int lane = tid & 63, wave = tid >> 6;
  const int quad = lane >> 4, l16 = lane & 15;
  const int wm = wave & 1, wo = wave >> 1;

  const int row0 = wave * 32 + (lane >> 2);
  const int ch8  = (((lane & 3) ^ ((lane >> 3) & 3)) << 3);
  const int ar0 = min(m0 + row0, M_ROWS - 1);
  const int ar1 = min(m0 + row0 + 16, M_ROWS - 1);
  const int br0 = o0 + row0;
  const int br1 = o0 + row0 + 16;
  const int dl0 = wave * 1024 + lane * 8;
  const int dl1 = dl0 + 512;

  GLD16(A + (size_t)ar0 * CH + ch8, &As[0][dl0]);
  GLD16(A + (size_t)ar1 * CH + ch8, &As[0][dl1]);
  GLD16(W + (size_t)br0 * CH + ch8, &Bs[0][dl0]);
  GLD16(W + (size_t)br1 * CH + ch8, &Bs[0][dl1]);

  const int rdc = ((quad ^ ((l16 >> 1) & 3)) << 3);
  const int rdA = (wm * 64 + l16) * 32 + rdc;
  const int rdB = (wo * 64 + l16) * 32 + rdc;

  f32x4 acc[4][4] = {};
  int cur = 0;
  for (int ks = 0; ks < CH / 32; ++ks) {
    __syncthreads();
    if (ks + 1 < CH / 32) {
      const int kc = (ks + 1) * 32 + ch8;
      const int nb = cur ^ 1;
      GLD16(A + (size_t)ar0 * CH + kc, &As[nb][dl0]);
      GLD16(A + (size_t)ar1 * CH + kc, &As[nb][dl1]);
      GLD16(W + (size_t)br0 * CH + kc, &Bs[nb][dl0]);
      GLD16(W + (size_t)br1 * CH + kc, &Bs[nb][dl1]);
    }
    f16x8 af[4], bf_[4];
    #pragma unroll
    for (int i = 0; i < 4; ++i)
      af[i] = *(const f16x8*)&As[cur][rdA + i * 512];
    #pragma unroll
    for (int j = 0; j < 4; ++j)
      bf_[j] = *(const f16x8*)&Bs[cur][rdB + j * 512];
    #pragma unroll
    for (int i = 0; i < 4; ++i)
      #pragma unroll
      for (int j = 0; j < 4; ++j)
        acc[i][j] = MFMA16(af[i], bf_[j], acc[i][j]);
    cur ^= 1;
  }

  #pragma unroll
  for (int i = 0; i < 4; ++i) {
    #pragma unroll
    for (int rr = 0; rr < 4; ++rr) {
      int m = m0 + wm * 64 + i * 16 + quad * 4 + rr;
      if (m >= M_ROWS) continue;
      #pragma unroll
      for (int j = 0; j < 4; ++j) {
        int o = o0 + wo * 64 + j * 16 + l16;
        float val = acc[i][j][rr] + ldin(bias, o, f32);
        if (f32) ((float*)out)[(size_t)m * CH + o] = val;
        else ((__hip_bfloat16*)out)[(size_t)m * CH + o] = __float2bfloat16(val);
      }
    }
  }
}

extern "C" void kernel_launch(void* const* d_in, const int* in_sizes, int n_in,
                              void* d_out, int out_size, void* d_ws, size_t ws_size,
                              hipStream_t stream) {
  const void* x     = d_in[0];
  const void* Wqkv  = d_in[1];
  const void* Wproj = d_in[2];
  const void* bproj = d_in[3];
  const void* Wpre  = d_in[4];
  const void* Wpost = d_in[5];

  int* flag = (int*)d_ws;
  _Float16* ws = (_Float16*)((char*)d_ws + 16);
  const size_t QFE = (size_t)16 * NH * 37 * 1024;   // 7,274,496 (frag-linear)
  const size_t KFE = (size_t)16 * NH * 40 * 1024;   // 7,864,320 (frag-linear)
  const size_t VTE = (size_t)16 * NH * 20 * 2048;   // 7,864,320 (m-tiled)
  const size_t OE  = (size_t)M_ROWS * CH;           // 7,090,176
  const size_t RPE = (size_t)16 * NH * 10 * NPAD;   // 1,136,640 f32
  const size_t EPB = (size_t)NH * 20 * EST;         // 4,546,560 f16 per batch

  _Float16* Xh  = ws;
  _Float16* Wqh = Xh + XHE;
  _Float16* Wph = Wqh + WQH;
  _Float16* q   = Wph + WPH;
  _Float16* k   = q + QFE;
  _Float16* vT  = k + KFE;
  _Float16* o1  = vT + VTE;
  float*    Rp  = (float*)(o1 + OE);

  // choose batch chunk from available workspace
  const size_t fixedB = 16 + ((size_t)XHE + WQH + WPH + QFE + KFE + VTE + OE)
                             * sizeof(_Float16) + RPE * sizeof(float);
  const size_t perB   = EPB * sizeof(_Float16);
  int cb = 16;
  while (cb > 1 && fixedB + (size_t)cb * perB > ws_size) cb >>= 1;

  _Float16* E = (_Float16*)(Rp + RPE);

  dim3 blk(256);
  hipLaunchKernelGGL(detect_dtype, dim3(1), blk, 0, stream,
                     (const unsigned short*)x, flag);
  hipLaunchKernelGGL(cvt_all, dim3((XHE + WQH + WPH) / 8 / 256 + 1), blk, 0,
                     stream, x, Wqkv, Wproj, Xh, flag);
  hipLaunchKernelGGL(gemm_qkv_mfma, dim3(18 * 73), blk, 0, stream,
                     Xh, Wqh, q, k, vT);
  {
    const int NPADS = 16 * NH * HD * 63 + 16 * NH * 63 * 64 + 16 * NH * 15 * 64;
    hipLaunchKernelGGL(zerofill_pads, dim3((NPADS + 255) / 256), blk, 0,
                       stream, vT, q, k);
  }
  for (int b0 = 0; b0 < 16; b0 += cb) {
    hipLaunchKernelGGL(qk_exp, dim3(370 * cb), blk, 0, stream,
                       q, k, Wpre, flag, E, Rp, b0, cb);
    hipLaunchKernelGGL(pv_mix3, dim3(73 * cb), blk, 0, stream,
                       E, vT, Rp, Wpost, flag, o1, b0, cb);
  }
  hipLaunchKernelGGL(gemm_proj_mfma, dim3(6 * 73), blk, 0, stream,
                     o1, Wph, bproj, flag, d_out);
}

// Round 12
// 391.466 us; speedup vs baseline: 3.4352x; 1.0125x over previous
//
#include <hip/hip_runtime.h>
#include <hip/hip_bf16.h>

#define NTOK 577
#define CH 768
#define NH 12
#define HD 64
#define M_ROWS 9232      // B * N
#define NPAD 592         // n pitch of E / Rp
#define ESP 72           // qk_exp LDS E-tile pitch (f16): 144 B = 9*16 aligned
#define EST 18944        // E2 per-(g,mc) region: NPAD * 32

#define XHE 7090176      // M_ROWS * CH
#define WQH 1769472      // 3 * CH * CH
#define WPH 589824       // CH * CH

typedef _Float16 f16x8 __attribute__((ext_vector_type(8)));
typedef _Float16 f16x4 __attribute__((ext_vector_type(4)));
typedef _Float16 f16x2 __attribute__((ext_vector_type(2)));
typedef float f32x4 __attribute__((ext_vector_type(4)));

#define MFMA16(a, b, c) __builtin_amdgcn_mfma_f32_16x16x32_f16((a), (b), (c), 0, 0, 0)

// barrier that does NOT drain vmcnt (LDS deps need lgkmcnt only)
#define BAR() asm volatile("s_waitcnt lgkmcnt(0)\n\ts_barrier" ::: "memory")

// async global->LDS, 16 B per lane. LDS dest must be wave-linear (base+lane*16).
#define GLD16(gp, lp) __builtin_amdgcn_global_load_lds(               \
    (const __attribute__((address_space(1))) void*)(gp),              \
    (__attribute__((address_space(3))) void*)(lp), 16, 0, 0)

// XCD-chunked bijective swizzle (m204)
__device__ __forceinline__ int xcd_swz(int lin, int G) {
  int q = G >> 3, r = G & 7;
  int x = lin & 7, i = lin >> 3;
  return (x < r ? x * (q + 1) : r * (q + 1) + (x - r) * q) + i;
}

__device__ __forceinline__ float bf2f(unsigned int u16) {
  union { unsigned int i; float f; } x; x.i = u16 << 16; return x.f;
}

__device__ __forceinline__ float ldin(const void* p, size_t i, bool f32) {
  return f32 ? ((const float*)p)[i]
             : __bfloat162float(((const __hip_bfloat16*)p)[i]);
}

__device__ __forceinline__ f16x8 ld8_cvt(const void* p, size_t idx, bool f32) {
  f16x8 r;
  if (f32) {
    const float* f = (const float*)p + idx;
    const float4 u = *(const float4*)f;
    const float4 v = *(const float4*)(f + 4);
    r[0]=(_Float16)u.x; r[1]=(_Float16)u.y; r[2]=(_Float16)u.z; r[3]=(_Float16)u.w;
    r[4]=(_Float16)v.x; r[5]=(_Float16)v.y; r[6]=(_Float16)v.z; r[7]=(_Float16)v.w;
  } else {
    const unsigned short* s = (const unsigned short*)p + idx;
    uint4 u = *(const uint4*)s;
    unsigned int w0=u.x, w1=u.y, w2=u.z, w3=u.w;
    r[0]=(_Float16)bf2f(w0&0xffffu); r[1]=(_Float16)bf2f(w0>>16);
    r[2]=(_Float16)bf2f(w1&0xffffu); r[3]=(_Float16)bf2f(w1>>16);
    r[4]=(_Float16)bf2f(w2&0xffffu); r[5]=(_Float16)bf2f(w2>>16);
    r[6]=(_Float16)bf2f(w3&0xffffu); r[7]=(_Float16)bf2f(w3>>16);
  }
  return r;
}

// ---- Kernel 0: detect input dtype (fp32 vs bf16).
__global__ void detect_dtype(const unsigned short* __restrict__ xs,
                             int* __restrict__ flag) {
  __shared__ int cnt;
  if (threadIdx.x == 0) cnt = 0;
  __syncthreads();
  int local = 0;
  for (int i = threadIdx.x; i < 4096; i += 256) {
    unsigned int u = xs[2 * i];
    unsigned int e = (u >> 7) & 0xFFu;
    if (e >= 140u) local++;
  }
  atomicAdd(&cnt, local);
  __syncthreads();
  if (threadIdx.x == 0) *flag = (cnt > 100) ? 1 : 0;
}

// ---- Kernel 0b: convert x | Wqkv | Wproj into one contiguous f16 region.
__global__ __launch_bounds__(256) void cvt_all(
    const void* __restrict__ x, const void* __restrict__ wq,
    const void* __restrict__ wp, _Float16* __restrict__ dst,
    const int* __restrict__ flagp)
{
  const bool f32 = (*flagp != 0);
  size_t i = (size_t)(blockIdx.x * 256 + threadIdx.x) * 8;
  if (i >= (size_t)(XHE + WQH + WPH)) return;
  const void* src; size_t off;
  if (i < XHE)            { src = x;  off = i; }
  else if (i < XHE + WQH) { src = wq; off = i - XHE; }
  else                    { src = wp; off = i - XHE - WQH; }
  *(f16x8*)(dst + i) = ld8_cvt(src, off, f32);
}

// ---- Kernel 1: qkv = x @ Wqkv^T, m97 structure. ALL outputs fragment/
// m-tiled:
//   qF[b][h][nt=n/16][dc=d/8][n%16][8]  (37 tiles)  — qk_exp A-frag read
//   kF[b][h][mt=m/16][dc][m%16][8]      (40 tiles)  — qk_exp B-frag read
//   vT2[b][g][mc=m/32][d 64][m%32]      (20 tiles)  — pv B-frag read
// Fragment a0 (d 0..31) at tile_base + lane*8; a1 (d 32..63) at +512.
__global__ __launch_bounds__(256) void gemm_qkv_mfma(
    const _Float16* __restrict__ X, const _Float16* __restrict__ W,
    _Float16* __restrict__ q, _Float16* __restrict__ k,
    _Float16* __restrict__ vT)
{
  __shared__ __align__(16) _Float16 As[2][128 * 32];
  __shared__ __align__(16) _Float16 Bs[2][128 * 32];
  const int swz = xcd_swz(blockIdx.x, 18 * 73);
  const int bx = swz % 18;                 // output-col tile (fast: shares X)
  const int m0 = (swz / 18) * 128;
  const int tid = threadIdx.x;
  const int lane = tid & 63, wave = tid >> 6;
  const int quad = lane >> 4, l16 = lane & 15;
  const int wm = wave & 1, wo = wave >> 1;
  const int t = bx / 6;                    // 0=q 1=k 2=v
  const int o0 = bx * 128;
  const int o0loc = o0 - t * CH;

  const int row0 = wave * 32 + (lane >> 2);
  const int ch8  = (((lane & 3) ^ ((lane >> 3) & 3)) << 3);  // swizzled src col
  const int ar0 = min(m0 + row0, M_ROWS - 1);
  const int ar1 = min(m0 + row0 + 16, M_ROWS - 1);
  const int br0 = o0 + row0;
  const int br1 = o0 + row0 + 16;
  const int dl0 = wave * 1024 + lane * 8;   // linear LDS dest (f16 idx)
  const int dl1 = dl0 + 512;

  GLD16(X + (size_t)ar0 * CH + ch8, &As[0][dl0]);
  GLD16(X + (size_t)ar1 * CH + ch8, &As[0][dl1]);
  GLD16(W + (size_t)br0 * CH + ch8, &Bs[0][dl0]);
  GLD16(W + (size_t)br1 * CH + ch8, &Bs[0][dl1]);

  const int rdc = ((quad ^ ((l16 >> 1) & 3)) << 3);      // swizzled read col
  const int rdA = (wm * 64 + l16) * 32 + rdc;
  const int rdB = (wo * 64 + l16) * 32 + rdc;

  f32x4 acc[4][4] = {};
  int cur = 0;
  for (int ks = 0; ks < CH / 32; ++ks) {
    __syncthreads();                       // drains vmcnt: tile ks ready
    if (ks + 1 < CH / 32) {
      const int kc = (ks + 1) * 32 + ch8;
      const int nb = cur ^ 1;
      GLD16(X + (size_t)ar0 * CH + kc, &As[nb][dl0]);
      GLD16(X + (size_t)ar1 * CH + kc, &As[nb][dl1]);
      GLD16(W + (size_t)br0 * CH + kc, &Bs[nb][dl0]);
      GLD16(W + (size_t)br1 * CH + kc, &Bs[nb][dl1]);
    }
    f16x8 af[4], bf_[4];
    #pragma unroll
    for (int i = 0; i < 4; ++i)
      af[i] = *(const f16x8*)&As[cur][rdA + i * 512];
    #pragma unroll
    for (int j = 0; j < 4; ++j)
      bf_[j] = *(const f16x8*)&Bs[cur][rdB + j * 512];
    #pragma unroll
    for (int i = 0; i < 4; ++i)
      #pragma unroll
      for (int j = 0; j < 4; ++j)
        acc[i][j] = MFMA16(af[i], bf_[j], acc[i][j]);
    cur ^= 1;
  }

  if (t < 2) {
    _Float16* dbuf = (t == 0) ? q : k;
    const int ntl = (t == 0) ? 37 : 40;
    #pragma unroll
    for (int i = 0; i < 4; ++i) {
      #pragma unroll
      for (int rr = 0; rr < 4; ++rr) {
        int m = m0 + wm * 64 + i * 16 + quad * 4 + rr;
        if (m >= M_ROWS) continue;
        int b = m / NTOK, n = m - b * NTOK;
        #pragma unroll
        for (int j = 0; j < 4; ++j) {
          int o = o0loc + wo * 64 + j * 16 + l16;
          int h = o >> 6, dd = o & 63;
          dbuf[((size_t)(b * NH + h) * ntl + (n >> 4)) * 1024
               + (dd >> 3) * 128 + (n & 15) * 8 + (dd & 7)] =
              (_Float16)acc[i][j][rr];
        }
      }
    }
  } else {
    // vT epilogue: per-wave LDS micro-transpose, then m-tiled store.
    __syncthreads();                       // LDS reads of K-loop done
    _Float16* scrb = &As[0][0] + wave * 512;
    #pragma unroll
    for (int i = 0; i < 4; ++i) {
      #pragma unroll
      for (int j = 0; j < 4; ++j) {
        _Float16* scr = scrb + (j & 1) * 256;
        f16x4 wv;
        wv[0] = (_Float16)acc[i][j][0]; wv[1] = (_Float16)acc[i][j][1];
        wv[2] = (_Float16)acc[i][j][2]; wv[3] = (_Float16)acc[i][j][3];
        *(f16x4*)&scr[l16 * 16 + quad * 4] = wv;   // scr[dd][n_loc]
        asm volatile("s_waitcnt lgkmcnt(0)" ::: "memory");
        f16x4 rv = *(const f16x4*)&scr[(lane >> 2) * 16 + (lane & 3) * 4];
        int oc = o0loc + wo * 64 + j * 16 + (lane >> 2);
        int hh = oc >> 6, ddg = oc & 63;
        int mbase = m0 + wm * 64 + i * 16 + (lane & 3) * 4;
        int bb = mbase / NTOK, nn2 = mbase - bb * NTOK;
        if (mbase + 3 < M_ROWS && nn2 + 3 < NTOK && !(nn2 & 1)
            && (nn2 & 31) <= 28) {
          _Float16* dst = &vT[((size_t)(bb * NH + hh) * 20 + (nn2 >> 5)) * 2048
                              + ddg * 32 + (nn2 & 31)];
          f16x2 lo2, hi2;
          lo2[0] = rv[0]; lo2[1] = rv[1];
          hi2[0] = rv[2]; hi2[1] = rv[3];
          *(f16x2*)dst = lo2;
          *(f16x2*)(dst + 2) = hi2;
        } else {
          #pragma unroll
          for (int e = 0; e < 4; ++e) {
            int m = mbase + e;
            if (m < M_ROWS) {
              int b2 = m / NTOK, n2 = m - b2 * NTOK;
              vT[((size_t)(b2 * NH + hh) * 20 + (n2 >> 5)) * 2048
                 + ddg * 32 + (n2 & 31)] = rv[e];
            }
          }
        }
      }
    }
  }
}

// ---- zero all pads: vT2 m in [577,640), kF m in [577,640), qF n in [577,592)
__global__ void zerofill_pads(_Float16* __restrict__ vT,
                              _Float16* __restrict__ qF,
                              _Float16* __restrict__ kF) {
  const int NV = 16 * NH * HD * 63;        // 774,144
  const int NK = 16 * NH * 63 * 64;        // 774,144
  const int NQ = 16 * NH * 15 * 64;        // 184,320
  int idx = blockIdx.x * 256 + threadIdx.x;
  if (idx < NV) {
    int r = idx / 63, c = idx % 63;        // r = bg*64+d
    int m = NTOK + c;
    int bg = r >> 6, d = r & 63;
    vT[((size_t)bg * 20 + (m >> 5)) * 2048 + d * 32 + (m & 31)] = (_Float16)0.f;
  } else if (idx < NV + NK) {
    int u = idx - NV;
    int bh = u / (63 * 64), v = u % (63 * 64);
    int m = NTOK + v / 64, d = v % 64;
    kF[((size_t)bh * 40 + (m >> 4)) * 1024
       + (d >> 3) * 128 + (m & 15) * 8 + (d & 7)] = (_Float16)0.f;
  } else if (idx < NV + NK + NQ) {
    int u = idx - NV - NK;
    int bh = u / (15 * 64), v = u % (15 * 64);
    int n = NTOK + v / 64, d = v % 64;
    qF[((size_t)bh * 37 + (n >> 4)) * 1024
       + (d >> 3) * 128 + (n & 15) * 8 + (d & 7)] = (_Float16)0.f;
  }
}

// ---- Kernel 2: QK^T + Wpre mix + exp -> E2 (m-tiled) + partial rowsums.
// q/k fragment-linear: a0/b0 at tile_base + lane*8 (d 0..31), a1/b1 at
// +512 (d 32..63). Pad rows zeroed -> no clamps.
__global__ __launch_bounds__(256) void qk_exp(
    const _Float16* __restrict__ q, const _Float16* __restrict__ k,
    const void* __restrict__ Wpre, const int* __restrict__ flagp,
    _Float16* __restrict__ E, float* __restrict__ Rp, int b0, int cb)
{
  const bool f32 = (*flagp != 0);
  __shared__ float wp[NH * NH];
  __shared__ _Float16 Es[NH * 16 * ESP];   // [g][n(16)][m(64)], pitch 72
  const int tid = threadIdx.x;
  if (tid < NH * NH) wp[tid] = ldin(Wpre, tid, f32) * 0.125f;  // fold scale
  __syncthreads();
  const int swz = xcd_swz(blockIdx.x, 370 * cb);
  const int bl = swz / 370;
  const int ny = (swz % 370) / 10;
  const int bx = swz % 10;
  const int lane = tid & 63, wave = tid >> 6;
  const int quad = lane >> 4, l16 = lane & 15;
  const int b = b0 + bl;
  const int n0 = ny * 16;
  const int m0 = bx * 64 + wave * 16;
  const _Float16* qp0 = q + ((size_t)(b * NH) * 37 + ny) * 1024 + lane * 8;
  const _Float16* kp0 = k + ((size_t)(b * NH) * 40 + bx * 4 + wave) * 1024
                          + lane * 8;
  f32x4 acc[NH];
  #pragma unroll
  for (int h = 0; h < NH; ++h) {
    const _Float16* qp = qp0 + (size_t)h * (37 * 1024);
    const _Float16* kp = kp0 + (size_t)h * (40 * 1024);
    f16x8 a0 = *(const f16x8*)qp;
    f16x8 bb0 = *(const f16x8*)kp;
    f16x8 a1 = *(const f16x8*)(qp + 512);
    f16x8 bb1 = *(const f16x8*)(kp + 512);
    f32x4 z = {0.f, 0.f, 0.f, 0.f};
    z = MFMA16(a0, bb0, z);
    acc[h] = MFMA16(a1, bb1, z);
  }
  const int mloc = wave * 16 + l16;          // col within 64-wide tile
  const bool valid = (m0 + l16 < NTOK);      // pad m -> exp=1 must be masked
  #pragma unroll
  for (int g = 0; g < NH; ++g) {
    float s0 = 0.f, s1 = 0.f, s2 = 0.f, s3 = 0.f;
    #pragma unroll
    for (int h = 0; h < NH; ++h) {
      float w = wp[g * NH + h];
      s0 += w * acc[h][0]; s1 += w * acc[h][1];
      s2 += w * acc[h][2]; s3 += w * acc[h][3];
    }
    Es[(g * 16 + quad * 4 + 0) * ESP + mloc] = (_Float16)(valid ? __expf(s0) : 0.f);
    Es[(g * 16 + quad * 4 + 1) * ESP + mloc] = (_Float16)(valid ? __expf(s1) : 0.f);
    Es[(g * 16 + quad * 4 + 2) * ESP + mloc] = (_Float16)(valid ? __expf(s2) : 0.f);
    Es[(g * 16 + quad * 4 + 3) * ESP + mloc] = (_Float16)(valid ? __expf(s3) : 0.f);
  }
  __syncthreads();
  // m-tiled store: per wave-iteration one (g,half) region of 16 n-rows x
  // 64 B = 1 KB contiguous.
  const int sub2 = tid & 3;
  const int nrow = (tid >> 2) & 15;
  const int rg0  = tid >> 6;                 // 0..3
  #pragma unroll
  for (int it = 0; it < 6; ++it) {
    int region = it * 4 + rg0;               // 0..23 = g*2+half
    int g = region >> 1, half = region & 1;
    f16x8 vv = *(const f16x8*)&Es[(g * 16 + nrow) * ESP + half * 32 + sub2 * 8];
    *(f16x8*)&E[((size_t)(bl * NH + g) * 20 + bx * 2 + half) * EST
                + (n0 + nrow) * 32 + sub2 * 8] = vv;
  }
  // partial rowsum of this block's 64 m-cols, per (g, n): Rp[b][g][bx][n]
  if (tid < NH * 16) {
    const _Float16* row = &Es[tid * ESP];
    float tot = 0.f;
    #pragma unroll
    for (int c = 0; c < 8; ++c) {
      f16x8 t = *(const f16x8*)&row[c * 8];
      #pragma unroll
      for (int j = 0; j < 8; ++j) tot += (float)t[j];
    }
    Rp[(((size_t)b * NH + (tid >> 4)) * 10 + bx) * NPAD + n0 + (tid & 15)] = tot;
  }
}

// ---- Kernel 3: pv_mix3 — 8-row n-tiles; E2/vT2 m-tiled dense-burst reads.
// DOUBLE-BUFFERED P2s + ONE barrier per m-chunk (round-11 had two): the
// write target of mix(i+1) is the buffer last read by MFMA(i-1), and BAR_i
// (after mix(i)) already orders those across all waves. This merges
// {MFMA(i) + E-prefetch(i+1) + mix(i+1)} into one barrier-free region so
// vT loads co-schedule with mix VALU (round-11 PMC: all pipes <25%,
// latency-bound; the "memory"-clobbered BARs serialized the two phases).
__global__ __launch_bounds__(256, 4) void pv_mix3(
    const _Float16* __restrict__ E, const _Float16* __restrict__ vT,
    const float* __restrict__ Rp, const void* __restrict__ Wpost,
    const int* __restrict__ flagp, _Float16* __restrict__ o1, int b0, int cb)
{
  const bool f32 = (*flagp != 0);
  __shared__ _Float16 P2s[2][NH * 8 * 128]; // dbuf [g][n8][m128], col ^ (n*8)
  __shared__ _Float16 w2s[NH * NH];
  __shared__ _Float16 rinvs[NH * 8];
  const int swz = xcd_swz(blockIdx.x, 73 * cb);
  const int bl = swz / 73;
  const int nx = swz % 73;
  const int tid = threadIdx.x;
  const int lane = tid & 63, w = tid >> 6;
  const int quad = lane >> 4, l16 = lane & 15;
  const int nn = l16 & 7;
  const int n0 = nx * 8;
  const int b = b0 + bl;
  if (tid < NH * NH) w2s[tid] = (_Float16)ldin(Wpost, tid, f32);
  if (tid < NH * 8) {
    float tot = 0.f;
    #pragma unroll
    for (int mb = 0; mb < 10; ++mb)
      tot += Rp[(((size_t)b * NH + (tid >> 3)) * 10 + mb) * NPAD + n0 + (tid & 7)];
    rinvs[tid] = (_Float16)(tot > 0.f ? 1.f / tot : 0.f);
  }
  __syncthreads();
  _Float16 rloc[NH];
  #pragma unroll
  for (int h = 0; h < NH; ++h) rloc[h] = rinvs[h * 8 + nn];

  f32x4 O[3][4];
  #pragma unroll
  for (int j = 0; j < 3; ++j)
    #pragma unroll
    for (int dt = 0; dt < 4; ++dt) O[j][dt] = (f32x4){0.f, 0.f, 0.f, 0.f};
  const int gg0 = w * 3;
  const int swzc = nn << 3;                 // column XOR for row nn

  const size_t eoff = (size_t)(n0 + nn) * 32 + quad * 8;
  const size_t ehead = (size_t)20 * EST;    // per-head stride in E2
  const size_t ebl = (size_t)(bl * NH) * ehead;
  f16x8 ev0[NH], ev1[NH];
  #pragma unroll
  for (int h = 0; h < NH; ++h)
    ev0[h] = *(const f16x8*)&E[ebl + h * ehead + (size_t)w * EST + eoff];
  #pragma unroll
  for (int i = 0; i < 5; ++i) {
    const int cur = i & 1;
    f16x8* curp = (i & 1) ? ev1 : ev0;
    f16x8* nxtp = (i & 1) ? ev0 : ev1;
    if (i + 1 < 5) {                        // prefetch next m-chunk's E
      #pragma unroll
      for (int h = 0; h < NH; ++h)
        nxtp[h] = *(const f16x8*)&E[ebl + h * ehead
                                    + (size_t)((i + 1) * 4 + w) * EST + eoff];
    }
    #pragma unroll
    for (int h = 0; h < NH; ++h) curp[h] *= rloc[h];
    #pragma unroll
    for (int gp = 0; gp < NH; ++gp) {
      f16x8 p = curp[0] * w2s[gp * NH + 0];
      #pragma unroll
      for (int h = 1; h < NH; ++h) p += curp[h] * w2s[gp * NH + h];
      if (l16 < 8)                          // lanes 8-15 hold duplicate data
        *(f16x8*)&P2s[cur][gp * 1024 + nn * 128
                           + ((w * 32 + quad * 8) ^ swzc)] = p;
    }
    BAR();                                  // mix(i) visible; also orders
                                            // MFMA(i-1) before mix(i+1)
    #pragma unroll
    for (int kc = 0; kc < 4; ++kc) {
      #pragma unroll
      for (int j = 0; j < 3; ++j) {
        const int g = gg0 + j;
        f16x8 a = *(const f16x8*)&P2s[cur][g * 1024 + nn * 128
                                           + ((kc * 32 + quad * 8) ^ swzc)];
        #pragma unroll
        for (int dt = 0; dt < 4; ++dt) {
          // vT2: contiguous 1 KB per (g, mc, dt) fragment load
          f16x8 bv = *(const f16x8*)(
              vT + ((size_t)(b * NH + g) * 20 + i * 4 + kc) * 2048
                 + (dt * 16 + l16) * 32 + quad * 8);
          O[j][dt] = MFMA16(a, bv, O[j][dt]);   // C rows 8-15 = dup of 0-7
        }
      }
    }
  }
  #pragma unroll
  for (int j = 0; j < 3; ++j)
    #pragma unroll
    for (int dt = 0; dt < 4; ++dt)
      #pragma unroll
      for (int r = 0; r < 4; ++r) {
        int n = quad * 4 + r;               // only quad<2 rows are real
        if (n < 8 && n0 + n < NTOK)
          o1[((size_t)b * NTOK + n0 + n) * CH + (gg0 + j) * HD + dt * 16 + l16] =
              (_Float16)O[j][dt][r];
      }
}

// ---- Kernel 4: out = o1 @ Wproj^T + bproj, m97-style staging.
__global__ __launch_bounds__(256) void gemm_proj_mfma(
    const _Float16* __restrict__ A, const _Float16* __restrict__ W,
    const void* __restrict__ bias, const int* __restrict__ flagp,
    void* __restrict__ out)
{
  const bool f32 = (*flagp != 0);
  __shared__ __align__(16) _Float16 As[2][128 * 32];
  __shared__ __align__(16) _Float16 Bs[2][128 * 32];
  const int swz = xcd_swz(blockIdx.x, 6 * 73);
  const int o0 = (swz % 6) * 128;
  const int m0 = (swz / 6) * 128;
  const int tid = threadIdx.x;
  const int lane = tid & 63, wave = tid >> 6;
  const int quad = lane >> 4, l16 = lane & 15;
  const int wm = wave & 1, wo = wave >> 1;

  const int row0 = wave * 32 + (lane >> 2);
  const int ch8  = (((lane & 3) ^ ((lane >> 3) & 3)) << 3);
  const int ar0 = min(m0 + row0, M_ROWS - 1);
  const int ar1 = min(m0 + row0 + 16, M_ROWS - 1);
  const int br0 = o0 + row0;
  const int br1 = o0 + row0 + 16;
  const int dl0 = wave * 1024 + lane * 8;
  const int dl1 = dl0 + 512;

  GLD16(A + (size_t)ar0 * CH + ch8, &As[0][dl0]);
  GLD16(A + (size_t)ar1 * CH + ch8, &As[0][dl1]);
  GLD16(W + (size_t)br0 * CH + ch8, &Bs[0][dl0]);
  GLD16(W + (size_t)br1 * CH + ch8, &Bs[0][dl1]);

  const int rdc = ((quad ^ ((l16 >> 1) & 3)) << 3);
  const int rdA = (wm * 64 + l16) * 32 + rdc;
  const int rdB = (wo * 64 + l16) * 32 + rdc;

  f32x4 acc[4][4] = {};
  int cur = 0;
  for (int ks = 0; ks < CH / 32; ++ks) {
    __syncthreads();
    if (ks + 1 < CH / 32) {
      const int kc = (ks + 1) * 32 + ch8;
      const int nb = cur ^ 1;
      GLD16(A + (size_t)ar0 * CH + kc, &As[nb][dl0]);
      GLD16(A + (size_t)ar1 * CH + kc, &As[nb][dl1]);
      GLD16(W + (size_t)br0 * CH + kc, &Bs[nb][dl0]);
      GLD16(W + (size_t)br1 * CH + kc, &Bs[nb][dl1]);
    }
    f16x8 af[4], bf_[4];
    #pragma unroll
    for (int i = 0; i < 4; ++i)
      af[i] = *(const f16x8*)&As[cur][rdA + i * 512];
    #pragma unroll
    for (int j = 0; j < 4; ++j)
      bf_[j] = *(const f16x8*)&Bs[cur][rdB + j * 512];
    #pragma unroll
    for (int i = 0; i < 4; ++i)
      #pragma unroll
      for (int j = 0; j < 4; ++j)
        acc[i][j] = MFMA16(af[i], bf_[j], acc[i][j]);
    cur ^= 1;
  }

  #pragma unroll
  for (int i = 0; i < 4; ++i) {
    #pragma unroll
    for (int rr = 0; rr < 4; ++rr) {
      int m = m0 + wm * 64 + i * 16 + quad * 4 + rr;
      if (m >= M_ROWS) continue;
      #pragma unroll
      for (int j = 0; j < 4; ++j) {
        int o = o0 + wo * 64 + j * 16 + l16;
        float val = acc[i][j][rr] + ldin(bias, o, f32);
        if (f32) ((float*)out)[(size_t)m * CH + o] = val;
        else ((__hip_bfloat16*)out)[(size_t)m * CH + o] = __float2bfloat16(val);
      }
    }
  }
}

extern "C" void kernel_launch(void* const* d_in, const int* in_sizes, int n_in,
                              void* d_out, int out_size, void* d_ws, size_t ws_size,
                              hipStream_t stream) {
  const void* x     = d_in[0];
  const void* Wqkv  = d_in[1];
  const void* Wproj = d_in[2];
  const void* bproj = d_in[3];
  const void* Wpre  = d_in[4];
  const void* Wpost = d_in[5];

  int* flag = (int*)d_ws;
  _Float16* ws = (_Float16*)((char*)d_ws + 16);
  const size_t QFE = (size_t)16 * NH * 37 * 1024;   // 7,274,496 (frag-linear)
  const size_t KFE = (size_t)16 * NH * 40 * 1024;   // 7,864,320 (frag-linear)
  const size_t VTE = (size_t)16 * NH * 20 * 2048;   // 7,864,320 (m-tiled)
  const size_t OE  = (size_t)M_ROWS * CH;           // 7,090,176
  const size_t RPE = (size_t)16 * NH * 10 * NPAD;   // 1,136,640 f32
  const size_t EPB = (size_t)NH * 20 * EST;         // 4,546,560 f16 per batch

  _Float16* Xh  = ws;
  _Float16* Wqh = Xh + XHE;
  _Float16* Wph = Wqh + WQH;
  _Float16* q   = Wph + WPH;
  _Float16* k   = q + QFE;
  _Float16* vT  = k + KFE;
  _Float16* o1  = vT + VTE;
  float*    Rp  = (float*)(o1 + OE);

  // choose batch chunk from available workspace
  const size_t fixedB = 16 + ((size_t)XHE + WQH + WPH + QFE + KFE + VTE + OE)
                             * sizeof(_Float16) + RPE * sizeof(float);
  const size_t perB   = EPB * sizeof(_Float16);
  int cb = 16;
  while (cb > 1 && fixedB + (size_t)cb * perB > ws_size) cb >>= 1;

  _Float16* E = (_Float16*)(Rp + RPE);

  dim3 blk(256);
  hipLaunchKernelGGL(detect_dtype, dim3(1), blk, 0, stream,
                     (const unsigned short*)x, flag);
  hipLaunchKernelGGL(cvt_all, dim3((XHE + WQH + WPH) / 8 / 256 + 1), blk, 0,
                     stream, x, Wqkv, Wproj, Xh, flag);
  hipLaunchKernelGGL(gemm_qkv_mfma, dim3(18 * 73), blk, 0, stream,
                     Xh, Wqh, q, k, vT);
  {
    const int NPADS = 16 * NH * HD * 63 + 16 * NH * 63 * 64 + 16 * NH * 15 * 64;
    hipLaunchKernelGGL(zerofill_pads, dim3((NPADS + 255) / 256), blk, 0,
                       stream, vT, q, k);
  }
  for (int b0 = 0; b0 < 16; b0 += cb) {
    hipLaunchKernelGGL(qk_exp, dim3(370 * cb), blk, 0, stream,
                       q, k, Wpre, flag, E, Rp, b0, cb);
    hipLaunchKernelGGL(pv_mix3, dim3(73 * cb), blk, 0, stream,
                       E, vT, Rp, Wpost, flag, o1, b0, cb);
  }
  hipLaunchKernelGGL(gemm_proj_mfma, dim3(6 * 73), blk, 0, stream,
                     o1, Wph, bproj, flag, d_out);
}

// Round 13
// 381.864 us; speedup vs baseline: 3.5215x; 1.0251x over previous
//
#include <hip/hip_runtime.h>
#include <hip/hip_bf16.h>

#define NTOK 577
#define CH 768
#define NH 12
#define HD 64
#define M_ROWS 9232      // B * N
#define NPAD 592         // n pitch of E / Rp
#define ESP 72           // qk_exp LDS E-tile pitch (f16): 144 B = 9*16 aligned
#define EST 18944        // E2 per-(g,mc) region: NPAD * 32

#define XHE 7090176      // M_ROWS * CH
#define WQH 1769472      // 3 * CH * CH
#define WPH 589824       // CH * CH

typedef _Float16 f16x8 __attribute__((ext_vector_type(8)));
typedef _Float16 f16x4 __attribute__((ext_vector_type(4)));
typedef _Float16 f16x2 __attribute__((ext_vector_type(2)));
typedef float f32x4 __attribute__((ext_vector_type(4)));

#define MFMA16(a, b, c) __builtin_amdgcn_mfma_f32_16x16x32_f16((a), (b), (c), 0, 0, 0)

// barrier that does NOT drain vmcnt (LDS deps need lgkmcnt only)
#define BAR() asm volatile("s_waitcnt lgkmcnt(0)\n\ts_barrier" ::: "memory")

// async global->LDS, 16 B per lane. LDS dest must be wave-linear (base+lane*16).
#define GLD16(gp, lp) __builtin_amdgcn_global_load_lds(               \
    (const __attribute__((address_space(1))) void*)(gp),              \
    (__attribute__((address_space(3))) void*)(lp), 16, 0, 0)

// XCD-chunked bijective swizzle (m204)
__device__ __forceinline__ int xcd_swz(int lin, int G) {
  int q = G >> 3, r = G & 7;
  int x = lin & 7, i = lin >> 3;
  return (x < r ? x * (q + 1) : r * (q + 1) + (x - r) * q) + i;
}

__device__ __forceinline__ float bf2f(unsigned int u16) {
  union { unsigned int i; float f; } x; x.i = u16 << 16; return x.f;
}

__device__ __forceinline__ float ldin(const void* p, size_t i, bool f32) {
  return f32 ? ((const float*)p)[i]
             : __bfloat162float(((const __hip_bfloat16*)p)[i]);
}

__device__ __forceinline__ f16x8 ld8_cvt(const void* p, size_t idx, bool f32) {
  f16x8 r;
  if (f32) {
    const float* f = (const float*)p + idx;
    const float4 u = *(const float4*)f;
    const float4 v = *(const float4*)(f + 4);
    r[0]=(_Float16)u.x; r[1]=(_Float16)u.y; r[2]=(_Float16)u.z; r[3]=(_Float16)u.w;
    r[4]=(_Float16)v.x; r[5]=(_Float16)v.y; r[6]=(_Float16)v.z; r[7]=(_Float16)v.w;
  } else {
    const unsigned short* s = (const unsigned short*)p + idx;
    uint4 u = *(const uint4*)s;
    unsigned int w0=u.x, w1=u.y, w2=u.z, w3=u.w;
    r[0]=(_Float16)bf2f(w0&0xffffu); r[1]=(_Float16)bf2f(w0>>16);
    r[2]=(_Float16)bf2f(w1&0xffffu); r[3]=(_Float16)bf2f(w1>>16);
    r[4]=(_Float16)bf2f(w2&0xffffu); r[5]=(_Float16)bf2f(w2>>16);
    r[6]=(_Float16)bf2f(w3&0xffffu); r[7]=(_Float16)bf2f(w3>>16);
  }
  return r;
}

// ---- Kernel 0: detect input dtype (fp32 vs bf16).
__global__ void detect_dtype(const unsigned short* __restrict__ xs,
                             int* __restrict__ flag) {
  __shared__ int cnt;
  if (threadIdx.x == 0) cnt = 0;
  __syncthreads();
  int local = 0;
  for (int i = threadIdx.x; i < 4096; i += 256) {
    unsigned int u = xs[2 * i];
    unsigned int e = (u >> 7) & 0xFFu;
    if (e >= 140u) local++;
  }
  atomicAdd(&cnt, local);
  __syncthreads();
  if (threadIdx.x == 0) *flag = (cnt > 100) ? 1 : 0;
}

// ---- Kernel 0b: convert x | Wqkv | Wproj into one contiguous f16 region.
__global__ __launch_bounds__(256) void cvt_all(
    const void* __restrict__ x, const void* __restrict__ wq,
    const void* __restrict__ wp, _Float16* __restrict__ dst,
    const int* __restrict__ flagp)
{
  const bool f32 = (*flagp != 0);
  size_t i = (size_t)(blockIdx.x * 256 + threadIdx.x) * 8;
  if (i >= (size_t)(XHE + WQH + WPH)) return;
  const void* src; size_t off;
  if (i < XHE)            { src = x;  off = i; }
  else if (i < XHE + WQH) { src = wq; off = i - XHE; }
  else                    { src = wp; off = i - XHE - WQH; }
  *(f16x8*)(dst + i) = ld8_cvt(src, off, f32);
}

// ---- Kernel 1: qkv = x @ Wqkv^T, m97 structure. ALL outputs fragment/
// m-tiled:
//   qF[b][h][nt=n/16][dc=d/8][n%16][8]  (37 tiles)  — qk_exp A-frag read
//   kF[b][h][mt=m/16][dc][m%16][8]      (40 tiles)  — qk_exp B-frag read
//   vT2[b][g][mc=m/32][d 64][m%32]      (20 tiles)  — pv B-frag read
// Fragment a0 (d 0..31) at tile_base + lane*8; a1 (d 32..63) at +512.
__global__ __launch_bounds__(256) void gemm_qkv_mfma(
    const _Float16* __restrict__ X, const _Float16* __restrict__ W,
    _Float16* __restrict__ q, _Float16* __restrict__ k,
    _Float16* __restrict__ vT)
{
  __shared__ __align__(16) _Float16 As[2][128 * 32];
  __shared__ __align__(16) _Float16 Bs[2][128 * 32];
  const int swz = xcd_swz(blockIdx.x, 18 * 73);
  const int bx = swz % 18;                 // output-col tile (fast: shares X)
  const int m0 = (swz / 18) * 128;
  const int tid = threadIdx.x;
  const int lane = tid & 63, wave = tid >> 6;
  const int quad = lane >> 4, l16 = lane & 15;
  const int wm = wave & 1, wo = wave >> 1;
  const int t = bx / 6;                    // 0=q 1=k 2=v
  const int o0 = bx * 128;
  const int o0loc = o0 - t * CH;

  const int row0 = wave * 32 + (lane >> 2);
  const int ch8  = (((lane & 3) ^ ((lane >> 3) & 3)) << 3);  // swizzled src col
  const int ar0 = min(m0 + row0, M_ROWS - 1);
  const int ar1 = min(m0 + row0 + 16, M_ROWS - 1);
  const int br0 = o0 + row0;
  const int br1 = o0 + row0 + 16;
  const int dl0 = wave * 1024 + lane * 8;   // linear LDS dest (f16 idx)
  const int dl1 = dl0 + 512;

  GLD16(X + (size_t)ar0 * CH + ch8, &As[0][dl0]);
  GLD16(X + (size_t)ar1 * CH + ch8, &As[0][dl1]);
  GLD16(W + (size_t)br0 * CH + ch8, &Bs[0][dl0]);
  GLD16(W + (size_t)br1 * CH + ch8, &Bs[0][dl1]);

  const int rdc = ((quad ^ ((l16 >> 1) & 3)) << 3);      // swizzled read col
  const int rdA = (wm * 64 + l16) * 32 + rdc;
  const int rdB = (wo * 64 + l16) * 32 + rdc;

  f32x4 acc[4][4] = {};
  int cur = 0;
  for (int ks = 0; ks < CH / 32; ++ks) {
    __syncthreads();                       // drains vmcnt: tile ks ready
    if (ks + 1 < CH / 32) {
      const int kc = (ks + 1) * 32 + ch8;
      const int nb = cur ^ 1;
      GLD16(X + (size_t)ar0 * CH + kc, &As[nb][dl0]);
      GLD16(X + (size_t)ar1 * CH + kc, &As[nb][dl1]);
      GLD16(W + (size_t)br0 * CH + kc, &Bs[nb][dl0]);
      GLD16(W + (size_t)br1 * CH + kc, &Bs[nb][dl1]);
    }
    f16x8 af[4], bf_[4];
    #pragma unroll
    for (int i = 0; i < 4; ++i)
      af[i] = *(const f16x8*)&As[cur][rdA + i * 512];
    #pragma unroll
    for (int j = 0; j < 4; ++j)
      bf_[j] = *(const f16x8*)&Bs[cur][rdB + j * 512];
    #pragma unroll
    for (int i = 0; i < 4; ++i)
      #pragma unroll
      for (int j = 0; j < 4; ++j)
        acc[i][j] = MFMA16(af[i], bf_[j], acc[i][j]);
    cur ^= 1;
  }

  if (t < 2) {
    _Float16* dbuf = (t == 0) ? q : k;
    const int ntl = (t == 0) ? 37 : 40;
    #pragma unroll
    for (int i = 0; i < 4; ++i) {
      #pragma unroll
      for (int rr = 0; rr < 4; ++rr) {
        int m = m0 + wm * 64 + i * 16 + quad * 4 + rr;
        if (m >= M_ROWS) continue;
        int b = m / NTOK, n = m - b * NTOK;
        #pragma unroll
        for (int j = 0; j < 4; ++j) {
          int o = o0loc + wo * 64 + j * 16 + l16;
          int h = o >> 6, dd = o & 63;
          dbuf[((size_t)(b * NH + h) * ntl + (n >> 4)) * 1024
               + (dd >> 3) * 128 + (n & 15) * 8 + (dd & 7)] =
              (_Float16)acc[i][j][rr];
        }
      }
    }
  } else {
    // vT epilogue: per-wave LDS micro-transpose, then m-tiled store.
    __syncthreads();                       // LDS reads of K-loop done
    _Float16* scrb = &As[0][0] + wave * 512;
    #pragma unroll
    for (int i = 0; i < 4; ++i) {
      #pragma unroll
      for (int j = 0; j < 4; ++j) {
        _Float16* scr = scrb + (j & 1) * 256;
        f16x4 wv;
        wv[0] = (_Float16)acc[i][j][0]; wv[1] = (_Float16)acc[i][j][1];
        wv[2] = (_Float16)acc[i][j][2]; wv[3] = (_Float16)acc[i][j][3];
        *(f16x4*)&scr[l16 * 16 + quad * 4] = wv;   // scr[dd][n_loc]
        asm volatile("s_waitcnt lgkmcnt(0)" ::: "memory");
        f16x4 rv = *(const f16x4*)&scr[(lane >> 2) * 16 + (lane & 3) * 4];
        int oc = o0loc + wo * 64 + j * 16 + (lane >> 2);
        int hh = oc >> 6, ddg = oc & 63;
        int mbase = m0 + wm * 64 + i * 16 + (lane & 3) * 4;
        int bb = mbase / NTOK, nn2 = mbase - bb * NTOK;
        if (mbase + 3 < M_ROWS && nn2 + 3 < NTOK && !(nn2 & 1)
            && (nn2 & 31) <= 28) {
          _Float16* dst = &vT[((size_t)(bb * NH + hh) * 20 + (nn2 >> 5)) * 2048
                              + ddg * 32 + (nn2 & 31)];
          f16x2 lo2, hi2;
          lo2[0] = rv[0]; lo2[1] = rv[1];
          hi2[0] = rv[2]; hi2[1] = rv[3];
          *(f16x2*)dst = lo2;
          *(f16x2*)(dst + 2) = hi2;
        } else {
          #pragma unroll
          for (int e = 0; e < 4; ++e) {
            int m = mbase + e;
            if (m < M_ROWS) {
              int b2 = m / NTOK, n2 = m - b2 * NTOK;
              vT[((size_t)(b2 * NH + hh) * 20 + (n2 >> 5)) * 2048
                 + ddg * 32 + (n2 & 31)] = rv[e];
            }
          }
        }
      }
    }
  }
}

// ---- zero all pads: vT2 m in [577,640), kF m in [577,640), qF n in [577,592)
__global__ void zerofill_pads(_Float16* __restrict__ vT,
                              _Float16* __restrict__ qF,
                              _Float16* __restrict__ kF) {
  const int NV = 16 * NH * HD * 63;        // 774,144
  const int NK = 16 * NH * 63 * 64;        // 774,144
  const int NQ = 16 * NH * 15 * 64;        // 184,320
  int idx = blockIdx.x * 256 + threadIdx.x;
  if (idx < NV) {
    int r = idx / 63, c = idx % 63;        // r = bg*64+d
    int m = NTOK + c;
    int bg = r >> 6, d = r & 63;
    vT[((size_t)bg * 20 + (m >> 5)) * 2048 + d * 32 + (m & 31)] = (_Float16)0.f;
  } else if (idx < NV + NK) {
    int u = idx - NV;
    int bh = u / (63 * 64), v = u % (63 * 64);
    int m = NTOK + v / 64, d = v % 64;
    kF[((size_t)bh * 40 + (m >> 4)) * 1024
       + (d >> 3) * 128 + (m & 15) * 8 + (d & 7)] = (_Float16)0.f;
  } else if (idx < NV + NK + NQ) {
    int u = idx - NV - NK;
    int bh = u / (15 * 64), v = u % (15 * 64);
    int n = NTOK + v / 64, d = v % 64;
    qF[((size_t)bh * 37 + (n >> 4)) * 1024
       + (d >> 3) * 128 + (n & 15) * 8 + (d & 7)] = (_Float16)0.f;
  }
}

// ---- Kernel 2: QK^T + Wpre mix + exp -> E2 (m-tiled) + partial rowsums.
// q/k fragment-linear: a0/b0 at tile_base + lane*8 (d 0..31), a1/b1 at
// +512 (d 32..63). Pad rows zeroed -> no clamps.
__global__ __launch_bounds__(256) void qk_exp(
    const _Float16* __restrict__ q, const _Float16* __restrict__ k,
    const void* __restrict__ Wpre, const int* __restrict__ flagp,
    _Float16* __restrict__ E, float* __restrict__ Rp, int b0, int cb)
{
  const bool f32 = (*flagp != 0);
  __shared__ float wp[NH * NH];
  __shared__ _Float16 Es[NH * 16 * ESP];   // [g][n(16)][m(64)], pitch 72
  const int tid = threadIdx.x;
  if (tid < NH * NH) wp[tid] = ldin(Wpre, tid, f32) * 0.125f;  // fold scale
  __syncthreads();
  const int swz = xcd_swz(blockIdx.x, 370 * cb);
  const int bl = swz / 370;
  const int ny = (swz % 370) / 10;
  const int bx = swz % 10;
  const int lane = tid & 63, wave = tid >> 6;
  const int quad = lane >> 4, l16 = lane & 15;
  const int b = b0 + bl;
  const int n0 = ny * 16;
  const int m0 = bx * 64 + wave * 16;
  const _Float16* qp0 = q + ((size_t)(b * NH) * 37 + ny) * 1024 + lane * 8;
  const _Float16* kp0 = k + ((size_t)(b * NH) * 40 + bx * 4 + wave) * 1024
                          + lane * 8;
  f32x4 acc[NH];
  #pragma unroll
  for (int h = 0; h < NH; ++h) {
    const _Float16* qp = qp0 + (size_t)h * (37 * 1024);
    const _Float16* kp = kp0 + (size_t)h * (40 * 1024);
    f16x8 a0 = *(const f16x8*)qp;
    f16x8 bb0 = *(const f16x8*)kp;
    f16x8 a1 = *(const f16x8*)(qp + 512);
    f16x8 bb1 = *(const f16x8*)(kp + 512);
    f32x4 z = {0.f, 0.f, 0.f, 0.f};
    z = MFMA16(a0, bb0, z);
    acc[h] = MFMA16(a1, bb1, z);
  }
  const int mloc = wave * 16 + l16;          // col within 64-wide tile
  const bool valid = (m0 + l16 < NTOK);      // pad m -> exp=1 must be masked
  #pragma unroll
  for (int g = 0; g < NH; ++g) {
    float s0 = 0.f, s1 = 0.f, s2 = 0.f, s3 = 0.f;
    #pragma unroll
    for (int h = 0; h < NH; ++h) {
      float w = wp[g * NH + h];
      s0 += w * acc[h][0]; s1 += w * acc[h][1];
      s2 += w * acc[h][2]; s3 += w * acc[h][3];
    }
    Es[(g * 16 + quad * 4 + 0) * ESP + mloc] = (_Float16)(valid ? __expf(s0) : 0.f);
    Es[(g * 16 + quad * 4 + 1) * ESP + mloc] = (_Float16)(valid ? __expf(s1) : 0.f);
    Es[(g * 16 + quad * 4 + 2) * ESP + mloc] = (_Float16)(valid ? __expf(s2) : 0.f);
    Es[(g * 16 + quad * 4 + 3) * ESP + mloc] = (_Float16)(valid ? __expf(s3) : 0.f);
  }
  __syncthreads();
  // m-tiled store: per wave-iteration one (g,half) region of 16 n-rows x
  // 64 B = 1 KB contiguous.
  const int sub2 = tid & 3;
  const int nrow = (tid >> 2) & 15;
  const int rg0  = tid >> 6;                 // 0..3
  #pragma unroll
  for (int it = 0; it < 6; ++it) {
    int region = it * 4 + rg0;               // 0..23 = g*2+half
    int g = region >> 1, half = region & 1;
    f16x8 vv = *(const f16x8*)&Es[(g * 16 + nrow) * ESP + half * 32 + sub2 * 8];
    *(f16x8*)&E[((size_t)(bl * NH + g) * 20 + bx * 2 + half) * EST
                + (n0 + nrow) * 32 + sub2 * 8] = vv;
  }
  // partial rowsum of this block's 64 m-cols, per (g, n): Rp[b][g][bx][n]
  if (tid < NH * 16) {
    const _Float16* row = &Es[tid * ESP];
    float tot = 0.f;
    #pragma unroll
    for (int c = 0; c < 8; ++c) {
      f16x8 t = *(const f16x8*)&row[c * 8];
      #pragma unroll
      for (int j = 0; j < 8; ++j) tot += (float)t[j];
    }
    Rp[(((size_t)b * NH + (tid >> 4)) * 10 + bx) * NPAD + n0 + (tid & 15)] = tot;
  }
}

// ---- Kernel 3 body: NC m-chunks starting at D0; 16-row tiles (A rows =
// l16, all 16 C rows valid — no duplication).
template<int NC, int D0>
__device__ __forceinline__ void pv4_body(
    const _Float16* __restrict__ E, const _Float16* __restrict__ vT,
    _Float16* P2s, const _Float16* w2s, const _Float16* rloc,
    f32x4 (&O)[3][4], size_t ebl, size_t ehead, size_t eoff,
    int b, int w, int quad, int l16, int gg0, int swzc)
{
  f16x8 ev0[NH], ev1[NH];
  #pragma unroll
  for (int h = 0; h < NH; ++h)
    ev0[h] = *(const f16x8*)&E[ebl + h * ehead + (size_t)(D0 * 4 + w) * EST + eoff];
  #pragma unroll
  for (int i = 0; i < NC; ++i) {
    const int dmt = D0 + i;
    f16x8* curp = (i & 1) ? ev1 : ev0;
    f16x8* nxtp = (i & 1) ? ev0 : ev1;
    if (i + 1 < NC) {                       // prefetch next m-chunk's E
      #pragma unroll
      for (int h = 0; h < NH; ++h)
        nxtp[h] = *(const f16x8*)&E[ebl + h * ehead
                                    + (size_t)((dmt + 1) * 4 + w) * EST + eoff];
    }
    #pragma unroll
    for (int h = 0; h < NH; ++h) curp[h] *= rloc[h];
    BAR();                                  // previous chunk's P2s readers done
    #pragma unroll
    for (int gp = 0; gp < NH; ++gp) {
      f16x8 p = curp[0] * w2s[gp * NH + 0];
      #pragma unroll
      for (int h = 1; h < NH; ++h) p += curp[h] * w2s[gp * NH + h];
      *(f16x8*)&P2s[gp * 2048 + l16 * 128 + ((w * 32 + quad * 8) ^ swzc)] = p;
    }
    BAR();
    #pragma unroll
    for (int kc = 0; kc < 4; ++kc) {
      #pragma unroll
      for (int j = 0; j < 3; ++j) {
        const int g = gg0 + j;
        f16x8 a = *(const f16x8*)&P2s[g * 2048 + l16 * 128
                                      + ((kc * 32 + quad * 8) ^ swzc)];
        #pragma unroll
        for (int dt = 0; dt < 4; ++dt) {
          // vT2: contiguous 1 KB per (g, mc, dt) fragment load
          f16x8 bv = *(const f16x8*)(
              vT + ((size_t)(b * NH + g) * 20 + dmt * 4 + kc) * 2048
                 + (dt * 16 + l16) * 32 + quad * 8);
          O[j][dt] = MFMA16(a, bv, O[j][dt]);
        }
      }
    }
  }
}

// ---- Kernel 3: pv_mix4 — 16-ROW n-tiles (full MFMA row utilization; the
// round-9..12 8-row tiles duplicated A rows 8-15 = half the mix VALU, vT
// traffic and MFMA wasted) + m-split z in {0,1} (chunks {0,1,2} / {3,4})
// to keep grid at 74 blocks/batch. Partial O in f16 to Op0/Op1; reduction
// fused into gemm_proj's A staging.
__global__ __launch_bounds__(256) void pv_mix4(
    const _Float16* __restrict__ E, const _Float16* __restrict__ vT,
    const float* __restrict__ Rp, const void* __restrict__ Wpost,
    const int* __restrict__ flagp, _Float16* __restrict__ Op0,
    _Float16* __restrict__ Op1, int b0, int cb)
{
  const bool f32 = (*flagp != 0);
  __shared__ _Float16 P2s[NH * 16 * 128];   // [g][n16][m128], col ^ ((n&7)*8)
  __shared__ _Float16 w2s[NH * NH];
  __shared__ _Float16 rinvs[NH * 16];
  const int swz = xcd_swz(blockIdx.x, 74 * cb);
  const int bl = swz / 74;
  const int rem = swz % 74;
  const int z = rem / 37;
  const int nx = rem % 37;
  const int tid = threadIdx.x;
  const int lane = tid & 63, w = tid >> 6;
  const int quad = lane >> 4, l16 = lane & 15;
  const int n0 = nx * 16;
  const int b = b0 + bl;
  if (tid < NH * NH) w2s[tid] = (_Float16)ldin(Wpost, tid, f32);
  if (tid < NH * 16) {
    float tot = 0.f;
    #pragma unroll
    for (int mb = 0; mb < 10; ++mb)
      tot += Rp[(((size_t)b * NH + (tid >> 4)) * 10 + mb) * NPAD + n0 + (tid & 15)];
    rinvs[tid] = (_Float16)(tot > 0.f ? 1.f / tot : 0.f);
  }
  __syncthreads();
  _Float16 rloc[NH];
  #pragma unroll
  for (int h = 0; h < NH; ++h) rloc[h] = rinvs[h * 16 + l16];

  f32x4 O[3][4];
  #pragma unroll
  for (int j = 0; j < 3; ++j)
    #pragma unroll
    for (int dt = 0; dt < 4; ++dt) O[j][dt] = (f32x4){0.f, 0.f, 0.f, 0.f};
  const int gg0 = w * 3;
  const int swzc = (l16 & 7) << 3;          // column XOR for row l16

  const size_t eoff = (size_t)(n0 + l16) * 32 + quad * 8;
  const size_t ehead = (size_t)20 * EST;    // per-head stride in E2
  const size_t ebl = (size_t)(bl * NH) * ehead;

  if (z == 0)
    pv4_body<3, 0>(E, vT, P2s, w2s, rloc, O, ebl, ehead, eoff,
                   b, w, quad, l16, gg0, swzc);
  else
    pv4_body<2, 3>(E, vT, P2s, w2s, rloc, O, ebl, ehead, eoff,
                   b, w, quad, l16, gg0, swzc);

  _Float16* __restrict__ Op = z ? Op1 : Op0;
  #pragma unroll
  for (int j = 0; j < 3; ++j)
    #pragma unroll
    for (int dt = 0; dt < 4; ++dt)
      #pragma unroll
      for (int r = 0; r < 4; ++r) {
        int nl = quad * 4 + r;              // all 16 rows valid
        if (n0 + nl < NTOK)
          Op[((size_t)b * NTOK + n0 + nl) * CH + (gg0 + j) * HD + dt * 16 + l16] =
              (_Float16)O[j][dt][r];
      }
}

// ---- Kernel 4: out = (Op0 + Op1) @ Wproj^T + bproj. A staging is
// register-summed (two f16x8 loads + add -> ds_write); B stays GLD16.
__global__ __launch_bounds__(256) void gemm_proj_mfma(
    const _Float16* __restrict__ A0, const _Float16* __restrict__ A1,
    const _Float16* __restrict__ W, const void* __restrict__ bias,
    const int* __restrict__ flagp, void* __restrict__ out)
{
  const bool f32 = (*flagp != 0);
  __shared__ __align__(16) _Float16 As[2][128 * 32];
  __shared__ __align__(16) _Float16 Bs[2][128 * 32];
  const int swz = xcd_swz(blockIdx.x, 6 * 73);
  const int o0 = (swz % 6) * 128;
  const int m0 = (swz / 6) * 128;
  const int tid = threadIdx.x;
  const int lane = tid & 63, wave = tid >> 6;
  const int quad = lane >> 4, l16 = lane & 15;
  const int wm = wave & 1, wo = wave >> 1;

  const int row0 = wave * 32 + (lane >> 2);
  const int ch8  = (((lane & 3) ^ ((lane >> 3) & 3)) << 3);
  const int ar0 = min(m0 + row0, M_ROWS - 1);
  const int ar1 = min(m0 + row0 + 16, M_ROWS - 1);
  const int br0 = o0 + row0;
  const int br1 = o0 + row0 + 16;
  const int dl0 = wave * 1024 + lane * 8;
  const int dl1 = dl0 + 512;

  {
    f16x8 p00 = *(const f16x8*)(A0 + (size_t)ar0 * CH + ch8);
    f16x8 p01 = *(const f16x8*)(A1 + (size_t)ar0 * CH + ch8);
    f16x8 p10 = *(const f16x8*)(A0 + (size_t)ar1 * CH + ch8);
    f16x8 p11 = *(const f16x8*)(A1 + (size_t)ar1 * CH + ch8);
    *(f16x8*)&As[0][dl0] = p00 + p01;
    *(f16x8*)&As[0][dl1] = p10 + p11;
  }
  GLD16(W + (size_t)br0 * CH + ch8, &Bs[0][dl0]);
  GLD16(W + (size_t)br1 * CH + ch8, &Bs[0][dl1]);

  const int rdc = ((quad ^ ((l16 >> 1) & 3)) << 3);
  const int rdA = (wm * 64 + l16) * 32 + rdc;
  const int rdB = (wo * 64 + l16) * 32 + rdc;

  f32x4 acc[4][4] = {};
  int cur = 0;
  for (int ks = 0; ks < CH / 32; ++ks) {
    __syncthreads();
    f16x8 s0, s1;
    const bool more = (ks + 1 < CH / 32);
    if (more) {
      const int kc = (ks + 1) * 32 + ch8;
      const int nb = cur ^ 1;
      GLD16(W + (size_t)br0 * CH + kc, &Bs[nb][dl0]);
      GLD16(W + (size_t)br1 * CH + kc, &Bs[nb][dl1]);
      f16x8 p00 = *(const f16x8*)(A0 + (size_t)ar0 * CH + kc);
      f16x8 p01 = *(const f16x8*)(A1 + (size_t)ar0 * CH + kc);
      f16x8 p10 = *(const f16x8*)(A0 + (size_t)ar1 * CH + kc);
      f16x8 p11 = *(const f16x8*)(A1 + (size_t)ar1 * CH + kc);
      s0 = p00 + p01;
      s1 = p10 + p11;
    }
    f16x8 af[4], bf_[4];
    #pragma unroll
    for (int i = 0; i < 4; ++i)
      af[i] = *(const f16x8*)&As[cur][rdA + i * 512];
    #pragma unroll
    for (int j = 0; j < 4; ++j)
      bf_[j] = *(const f16x8*)&Bs[cur][rdB + j * 512];
    if (more) {
      const int nb = cur ^ 1;
      *(f16x8*)&As[nb][dl0] = s0;
      *(f16x8*)&As[nb][dl1] = s1;
    }
    #pragma unroll
    for (int i = 0; i < 4; ++i)
      #pragma unroll
      for (int j = 0; j < 4; ++j)
        acc[i][j] = MFMA16(af[i], bf_[j], acc[i][j]);
    cur ^= 1;
  }

  #pragma unroll
  for (int i = 0; i < 4; ++i) {
    #pragma unroll
    for (int rr = 0; rr < 4; ++rr) {
      int m = m0 + wm * 64 + i * 16 + quad * 4 + rr;
      if (m >= M_ROWS) continue;
      #pragma unroll
      for (int j = 0; j < 4; ++j) {
        int o = o0 + wo * 64 + j * 16 + l16;
        float val = acc[i][j][rr] + ldin(bias, o, f32);
        if (f32) ((float*)out)[(size_t)m * CH + o] = val;
        else ((__hip_bfloat16*)out)[(size_t)m * CH + o] = __float2bfloat16(val);
      }
    }
  }
}

extern "C" void kernel_launch(void* const* d_in, const int* in_sizes, int n_in,
                              void* d_out, int out_size, void* d_ws, size_t ws_size,
                              hipStream_t stream) {
  const void* x     = d_in[0];
  const void* Wqkv  = d_in[1];
  const void* Wproj = d_in[2];
  const void* bproj = d_in[3];
  const void* Wpre  = d_in[4];
  const void* Wpost = d_in[5];

  int* flag = (int*)d_ws;
  _Float16* ws = (_Float16*)((char*)d_ws + 16);
  const size_t QFE = (size_t)16 * NH * 37 * 1024;   // 7,274,496 (frag-linear)
  const size_t KFE = (size_t)16 * NH * 40 * 1024;   // 7,864,320 (frag-linear)
  const size_t VTE = (size_t)16 * NH * 20 * 2048;   // 7,864,320 (m-tiled)
  const size_t OE  = (size_t)M_ROWS * CH;           // 7,090,176
  const size_t RPE = (size_t)16 * NH * 10 * NPAD;   // 1,136,640 f32
  const size_t EPB = (size_t)NH * 20 * EST;         // 4,546,560 f16 per batch

  _Float16* Xh  = ws;
  _Float16* Wqh = Xh + XHE;
  _Float16* Wph = Wqh + WQH;
  _Float16* q   = Wph + WPH;
  _Float16* k   = q + QFE;
  _Float16* vT  = k + KFE;
  _Float16* Op0 = vT + VTE;
  _Float16* Op1 = Op0 + OE;
  float*    Rp  = (float*)(Op1 + OE);

  // choose batch chunk from available workspace
  const size_t fixedB = 16 + ((size_t)XHE + WQH + WPH + QFE + KFE + VTE + 2 * OE)
                             * sizeof(_Float16) + RPE * sizeof(float);
  const size_t perB   = EPB * sizeof(_Float16);
  int cb = 16;
  while (cb > 1 && fixedB + (size_t)cb * perB > ws_size) cb >>= 1;

  _Float16* E = (_Float16*)(Rp + RPE);

  dim3 blk(256);
  hipLaunchKernelGGL(detect_dtype, dim3(1), blk, 0, stream,
                     (const unsigned short*)x, flag);
  hipLaunchKernelGGL(cvt_all, dim3((XHE + WQH + WPH) / 8 / 256 + 1), blk, 0,
                     stream, x, Wqkv, Wproj, Xh, flag);
  hipLaunchKernelGGL(gemm_qkv_mfma, dim3(18 * 73), blk, 0, stream,
                     Xh, Wqh, q, k, vT);
  {
    const int NPADS = 16 * NH * HD * 63 + 16 * NH * 63 * 64 + 16 * NH * 15 * 64;
    hipLaunchKernelGGL(zerofill_pads, dim3((NPADS + 255) / 256), blk, 0,
                       stream, vT, q, k);
  }
  for (int b0 = 0; b0 < 16; b0 += cb) {
    hipLaunchKernelGGL(qk_exp, dim3(370 * cb), blk, 0, stream,
                       q, k, Wpre, flag, E, Rp, b0, cb);
    hipLaunchKernelGGL(pv_mix4, dim3(74 * cb), blk, 0, stream,
                       E, vT, Rp, Wpost, flag, Op0, Op1, b0, cb);
  }
  hipLaunchKernelGGL(gemm_proj_mfma, dim3(6 * 73), blk, 0, stream,
                     Op0, Op1, Wph, bproj, flag, d_out);
}